// Round 7
// baseline (1583.013 us; speedup 1.0000x reference)
//
#include <hip/hip_runtime.h>
#include <hip/hip_bf16.h>

#define KS 5
#define K3 125

__device__ inline float4 f4fma(float a, float4 b, float4 c) {
    c.x = fmaf(a, b.x, c.x); c.y = fmaf(a, b.y, c.y);
    c.z = fmaf(a, b.z, c.z); c.w = fmaf(a, b.w, c.w);
    return c;
}

// ---------------------------------------------------------------------------
// Inline basis helpers
// ---------------------------------------------------------------------------
__device__ inline void edge_basis(const float* __restrict__ pseudo, int e,
                                  float* bs, int* ks) {
    float fr[3];
    int bot[3];
#pragma unroll
    for (int d = 0; d < 3; ++d) {
        float v = pseudo[e * 3 + d] * (float)(KS - 1);
        float fl = fminf(floorf(v), (float)(KS - 2));
        fr[d] = v - fl;
        bot[d] = (int)fl;
    }
    const int strides[3] = {1, KS, KS * KS};
#pragma unroll
    for (int s = 0; s < 8; ++s) {
        float b = 1.f;
        int w = 0;
#pragma unroll
        for (int d = 0; d < 3; ++d) {
            int bit = (s >> d) & 1;
            b *= bit ? fr[d] : (1.f - fr[d]);
            w += (bot[d] + bit) * strides[d];
        }
        bs[s] = b;
        ks[s] = w;
    }
}

__device__ inline int edge_bucket(const float* __restrict__ pseudo, int e) {
    int kb = 0;
#pragma unroll
    for (int d = 0; d < 3; ++d) {
        float v = pseudo[e * 3 + d] * (float)(KS - 1);
        int fl = (int)fminf(floorf(v), (float)(KS - 2));
        kb += fl << (2 * d);
    }
    return kb;
}

// ---------------------------------------------------------------------------
// Fused pass 1 (all 4 levels): 64-bucket histogram + degree.
// ---------------------------------------------------------------------------
__global__ __launch_bounds__(256) void hist_deg_all(
    const float* __restrict__ p0, const float* __restrict__ p1,
    const float* __restrict__ p2, const float* __restrict__ p3,
    const int* __restrict__ d0, const int* __restrict__ d1,
    const int* __restrict__ d2, const int* __restrict__ d3,
    int* __restrict__ hist, float* __restrict__ degAll) {
    int b = blockIdx.x;
    int l, lb, E, dof;
    const float* ps;
    const int* ds;
    if (b < 512)      { l = 0; lb = b;       ps = p0; ds = d0; E = 131072; dof = 0; }
    else if (b < 640) { l = 1; lb = b - 512; ps = p1; ds = d1; E = 32768;  dof = 16384; }
    else if (b < 672) { l = 2; lb = b - 640; ps = p2; ds = d2; E = 8192;   dof = 20480; }
    else              { l = 3; lb = b - 672; ps = p3; ds = d3; E = 2048;   dof = 21504; }
    __shared__ int h[64];
    int t = threadIdx.x;
    if (t < 64) h[t] = 0;
    __syncthreads();
    int e = lb * 256 + t;
    if (e < E) {
        atomicAdd(&h[edge_bucket(ps, e)], 1);
        atomicAdd(&degAll[dof + ds[e]], 1.f);
    }
    __syncthreads();
    if (t < 64 && h[t]) atomicAdd(&hist[l * 64 + t], h[t]);
}

// ---------------------------------------------------------------------------
// Fused pass 2: bucket layout per level (blockIdx = level).
// ---------------------------------------------------------------------------
__global__ void scan_pad_all(const int* __restrict__ hist, int* __restrict__ gcur,
                             int* __restrict__ tileOf, int* __restrict__ pack) {
    const int TBv[4] = {0, 2112, 2112 + 576, 2112 + 576 + 192};
    int l = blockIdx.x;
    int tileBase = TBv[l];
    __shared__ int sh[64];
    int t = threadIdx.x;
    int cnt = hist[l * 64 + t];
    int tiles = (cnt + 63) >> 6;
    sh[t] = tiles;
    __syncthreads();
    for (int d = 1; d < 64; d <<= 1) {
        int v = (t >= d) ? sh[t - d] : 0;
        __syncthreads();
        sh[t] += v;
        __syncthreads();
    }
    int tb = tileBase + sh[t] - tiles;
    int eb = tb * 64;
    gcur[l * 64 + t] = eb;
    for (int q = 0; q < tiles; ++q) tileOf[tb + q] = t;
    for (int idx = eb + cnt; idx < eb + tiles * 64; ++idx) pack[idx] = -1;
}

// ---------------------------------------------------------------------------
// Fused pass 3: block-local counting sort of edges (1024 edges/block).
// ---------------------------------------------------------------------------
__global__ __launch_bounds__(256) void scatter_all(
    const float* __restrict__ p0, const float* __restrict__ p1,
    const float* __restrict__ p2, const float* __restrict__ p3,
    int* __restrict__ gcur, int* __restrict__ pack) {
    int b = blockIdx.x;
    int l, lb, E;
    const float* ps;
    if (b < 128)      { l = 0; lb = b;       ps = p0; E = 131072; }
    else if (b < 160) { l = 1; lb = b - 128; ps = p1; E = 32768; }
    else if (b < 168) { l = 2; lb = b - 160; ps = p2; E = 8192; }
    else              { l = 3; lb = b - 168; ps = p3; E = 2048; }
    int* gc = gcur + l * 64;
    __shared__ int h[64], lbk[64], gb[64], sh[64];
    __shared__ int sp[1024];
    __shared__ unsigned char skk[1024];
    int t = threadIdx.x;
    int ebase = lb * 1024;
    int kbv[4];
    if (t < 64) h[t] = 0;
    __syncthreads();
#pragma unroll
    for (int j = 0; j < 4; ++j) {
        int e = ebase + j * 256 + t;
        if (e < E) {
            kbv[j] = edge_bucket(ps, e);
            atomicAdd(&h[kbv[j]], 1);
        } else
            kbv[j] = -1;
    }
    __syncthreads();
    if (t < 64) sh[t] = h[t];
    __syncthreads();
    for (int d = 1; d < 64; d <<= 1) {
        int v = (t < 64 && t >= d) ? sh[t - d] : 0;
        __syncthreads();
        if (t < 64) sh[t] += v;
        __syncthreads();
    }
    if (t < 64) {
        int c = h[t];
        lbk[t] = sh[t] - c;
        gb[t] = c ? atomicAdd(&gc[t], c) : 0;
        h[t] = 0;
    }
    __syncthreads();
#pragma unroll
    for (int j = 0; j < 4; ++j) {
        int e = ebase + j * 256 + t;
        if (kbv[j] >= 0) {
            int pos = lbk[kbv[j]] + atomicAdd(&h[kbv[j]], 1);
            sp[pos] = e;
            skk[pos] = (unsigned char)kbv[j];
        }
    }
    __syncthreads();
    int Pb = E - ebase;
    if (Pb > 1024) Pb = 1024;
    for (int j = t; j < Pb; j += 256) {
        int k = skk[j];
        pack[gb[k] + (j - lbk[k])] = sp[j];
    }
}

// ---------------------------------------------------------------------------
// Fused conv1 (in_c = 1)
// ---------------------------------------------------------------------------
__global__ __launch_bounds__(256) void conv1_fused(const float* __restrict__ x,
                                                   const int* __restrict__ src,
                                                   const int* __restrict__ dst,
                                                   const float* __restrict__ pseudo,
                                                   const float* __restrict__ W,
                                                   float* __restrict__ out, int E) {
    const int lane = threadIdx.x & 63;
    const int wid = threadIdx.x >> 6;
    const int sub = lane >> 5;
    const int o = lane & 31;
    int e = (blockIdx.x * 4 + wid) * 2 + sub;
    if (e >= E) return;
    float bs[8];
    int ks[8];
    edge_basis(pseudo, e, bs, ks);
    float acc = 0.f;
#pragma unroll
    for (int s = 0; s < 8; ++s) acc = fmaf(bs[s], W[ks[s] * 32 + o], acc);
    atomicAdd(&out[(size_t)dst[e] * 32 + o], acc * x[src[e]]);
}

// ---------------------------------------------------------------------------
// Cube GEMV, vector-load W feed. Sub-group of G=OUT_C/4 lanes per edge;
// lane holds a float4 accumulator (no LDS -> high occupancy). Per slot the
// lane rescales its own x-quad by b_s and broadcasts components via __shfl;
// W comes in as lane-varying float4 loads (L1-hot: all edges in the tile
// share one 2x2x2 cube). One coalesced atomic flush per edge at the end.
// ---------------------------------------------------------------------------
template <int IN_C, int OUT_C>
__global__ __launch_bounds__(256) void gemv_cube_v(
    const float* __restrict__ x, const int* __restrict__ src,
    const int* __restrict__ dst, const float* __restrict__ pseudo,
    const int* __restrict__ pack, const int* __restrict__ tileOf,
    const float* __restrict__ W, float* __restrict__ out, int tileBase) {
    constexpr int G = OUT_C / 4;   // lanes per edge
    constexpr int EPW = 64 / G;    // edges per wave
    constexpr int EPB = EPW * 4;   // edges per block (4 waves)
    constexpr int BPT = 64 / EPB;  // blocks per tile
    const int tid = threadIdx.x;
    const int wv = tid >> 6, lane = tid & 63;
    const int sub = lane / G, og = lane % G;
    int t = tileBase + blockIdx.x / BPT;
    int kb = tileOf[t];
    if (kb < 0) return;  // pad tile (uniform exit)
    kb = __builtin_amdgcn_readfirstlane(kb);
    const int kbase = (kb & 3) + 5 * ((kb >> 2) & 3) + 25 * ((kb >> 4) & 3);
    const int eoff = (blockIdx.x % BPT) * EPB + wv * EPW + sub;
    int e = pack[t * 64 + eoff];
    float bs[8];
    float4 xq = make_float4(0.f, 0.f, 0.f, 0.f);
    int dn = -1;
    if (e >= 0) {
        float fr[3];
#pragma unroll
        for (int d = 0; d < 3; ++d) {
            float v = pseudo[e * 3 + d] * (float)(KS - 1);
            float fl = fminf(floorf(v), (float)(KS - 2));
            fr[d] = v - fl;
        }
#pragma unroll
        for (int s = 0; s < 8; ++s) {
            float b = 1.f;
#pragma unroll
            for (int d = 0; d < 3; ++d) b *= ((s >> d) & 1) ? fr[d] : (1.f - fr[d]);
            bs[s] = b;
        }
        int sn = src[e];
        dn = dst[e];
        if (og * 4 < IN_C) xq = *(const float4*)(x + (size_t)sn * IN_C + og * 4);
    } else {
#pragma unroll
        for (int s = 0; s < 8; ++s) bs[s] = 0.f;
    }
    constexpr int CUBE = IN_C * OUT_C;
    const float* __restrict__ Wb = W + (size_t)kbase * CUBE;
    float4 acc = make_float4(0.f, 0.f, 0.f, 0.f);
    const int lbase = sub * G;
#pragma unroll
    for (int s = 0; s < 8; ++s) {
        const float4* __restrict__ Wc =
            (const float4*)(Wb + ((s & 1) + 5 * ((s >> 1) & 1) + 25 * ((s >> 2) & 1)) * CUBE);
        float4 bx;
        bx.x = bs[s] * xq.x; bx.y = bs[s] * xq.y;
        bx.z = bs[s] * xq.z; bx.w = bs[s] * xq.w;
#pragma unroll
        for (int io = 0; io < IN_C / 4; ++io) {
            float b0 = __shfl(bx.x, lbase + io);
            float b1 = __shfl(bx.y, lbase + io);
            float b2 = __shfl(bx.z, lbase + io);
            float b3 = __shfl(bx.w, lbase + io);
            acc = f4fma(b0, Wc[(io * 4 + 0) * G + og], acc);
            acc = f4fma(b1, Wc[(io * 4 + 1) * G + og], acc);
            acc = f4fma(b2, Wc[(io * 4 + 2) * G + og], acc);
            acc = f4fma(b3, Wc[(io * 4 + 3) * G + og], acc);
        }
    }
    if (dn >= 0) {
        float* o = out + (size_t)dn * OUT_C + og * 4;
        atomicAdd(o + 0, acc.x);
        atomicAdd(o + 1, acc.y);
        atomicAdd(o + 2, acc.z);
        atomicAdd(o + 3, acc.w);
    }
}

// ---------------------------------------------------------------------------
// Edge-centric conv with inline basis (fallback path only)
// ---------------------------------------------------------------------------
template <int IN_C, int OUT_C>
__global__ __launch_bounds__(256) void conv_edges_inline(
    const float* __restrict__ x, const int* __restrict__ src,
    const int* __restrict__ dst, const float* __restrict__ pseudo,
    const float* __restrict__ W, float* __restrict__ out, int E) {
    const int lane = threadIdx.x & 63;
    const int wid = threadIdx.x >> 6;
    constexpr int EPW = 64 / OUT_C;
    const int sub = (EPW == 2) ? (lane >> 5) : 0;
    const int o = lane & (OUT_C - 1);
    long e = (long)(blockIdx.x * (blockDim.x >> 6) + wid) * EPW + sub;
    if (e >= E) return;
    float bs[8];
    int ks[8];
    edge_basis(pseudo, e, bs, ks);
    const int s_ = src[e];
    const int d_ = dst[e];
    float xv = (o < IN_C) ? x[s_ * IN_C + o] : 0.f;
    float acc = 0.f;
#pragma unroll
    for (int s = 0; s < 8; ++s) {
        const float b = bs[s];
        const float* Wk = W + (long)ks[s] * IN_C * OUT_C;
#pragma unroll 4
        for (int i = 0; i < IN_C; ++i) {
            float xi = __shfl(xv, i, OUT_C);
            acc = fmaf(b * xi, Wk[i * OUT_C + o], acc);
        }
    }
    atomicAdd(&out[(long)d_ * OUT_C + o], acc);
}

__global__ void deg_kernel(const int* __restrict__ dst, float* __restrict__ deg, int E) {
    int e = blockIdx.x * blockDim.x + threadIdx.x;
    if (e >= E) return;
    atomicAdd(&deg[dst[e]], 1.0f);
}

// ---------------------------------------------------------------------------
// Finalize: out = scatter/max(deg,1) + x@R + B, then ELU. In-place.
// ---------------------------------------------------------------------------
template <int IN_C, int OUT_C>
__global__ __launch_bounds__(256) void finalize_k(
    const float* __restrict__ xin, const float* __restrict__ R,
    const float* __restrict__ B, const float* __restrict__ deg,
    float* __restrict__ out, int n) {
    const int lane = threadIdx.x & 63;
    const int wid = threadIdx.x >> 6;
    constexpr int EPW = 64 / OUT_C;
    const int sub = (EPW == 2) ? (lane >> 5) : 0;
    const int o = lane & (OUT_C - 1);
    int j = (blockIdx.x * (blockDim.x >> 6) + wid) * EPW + sub;
    if (j >= n) return;
    float xv = (o < IN_C) ? xin[j * IN_C + o] : 0.f;
    float acc = B[o];
#pragma unroll 4
    for (int i = 0; i < IN_C; ++i) {
        float xi = __shfl(xv, i, OUT_C);
        acc = fmaf(xi, R[i * OUT_C + o], acc);
    }
    float d = fmaxf(deg[j], 1.f);
    float v = out[j * OUT_C + o] / d + acc;
    out[j * OUT_C + o] = (v > 0.f) ? v : expm1f(v);
}

// ---------------------------------------------------------------------------
// Segment max pooling (monotone uint atomicMax; every slot provably written)
// ---------------------------------------------------------------------------
__global__ void pool_scatter(const float* __restrict__ h, const int* __restrict__ cluster,
                             unsigned* __restrict__ pool, int n, int logC) {
    int idx = blockIdx.x * blockDim.x + threadIdx.x;
    if (idx >= (n << logC)) return;
    int j = idx >> logC;
    int c = idx & ((1 << logC) - 1);
    float f = h[idx];
    int b = __float_as_int(f);
    unsigned enc = (b >= 0) ? ((unsigned)b | 0x80000000u) : ~((unsigned)b);
    atomicMax(&pool[(cluster[j] << logC) + c], enc);
}

__global__ void pool_decode(const unsigned* __restrict__ pool, float* __restrict__ out, int total) {
    int idx = blockIdx.x * blockDim.x + threadIdx.x;
    if (idx >= total) return;
    unsigned u = pool[idx];
    int b = (u & 0x80000000u) ? (int)(u & 0x7FFFFFFFu) : (int)(~u);
    out[idx] = __int_as_float(b);
}

// ---------------------------------------------------------------------------
// Head: mean(64x64) -> fc1 -> fc2 -> log_softmax
// ---------------------------------------------------------------------------
__global__ void head_kernel(const float* __restrict__ h, const float* __restrict__ fc1w,
                            const float* __restrict__ fc1b, const float* __restrict__ fc2w,
                            const float* __restrict__ fc2b, float* __restrict__ out) {
    __shared__ float m[64], t[64], u[10];
    int lane = threadIdx.x;
    float s = 0.f;
    for (int j = 0; j < 64; ++j) s += h[j * 64 + lane];
    m[lane] = s * (1.f / 64.f);
    __syncthreads();
    float a = fc1b[lane];
    for (int i = 0; i < 64; ++i) a = fmaf(m[i], fc1w[i * 64 + lane], a);
    t[lane] = a;
    __syncthreads();
    if (lane < 10) {
        float b = fc2b[lane];
        for (int i = 0; i < 64; ++i) b = fmaf(t[i], fc2w[i * 10 + lane], b);
        u[lane] = b;
    }
    __syncthreads();
    if (lane < 10) {
        float mx = u[0];
        for (int i = 1; i < 10; ++i) mx = fmaxf(mx, u[i]);
        float se = 0.f;
        for (int i = 0; i < 10; ++i) se += expf(u[i] - mx);
        out[lane] = u[lane] - mx - logf(se);
    }
}

// ---------------------------------------------------------------------------
// Host side
// ---------------------------------------------------------------------------
static inline int cdiv(int a, int b) { return (a + b - 1) / b; }

extern "C" void kernel_launch(void* const* d_in, const int* in_sizes, int n_in,
                              void* d_out, int out_size, void* d_ws, size_t ws_size,
                              hipStream_t stream) {
    const float* x = (const float*)d_in[0];
    const int* src[4] = {(const int*)d_in[1], (const int*)d_in[5], (const int*)d_in[9], (const int*)d_in[13]};
    const int* dst[4] = {(const int*)d_in[2], (const int*)d_in[6], (const int*)d_in[10], (const int*)d_in[14]};
    const float* pseudo[4] = {(const float*)d_in[3], (const float*)d_in[7], (const float*)d_in[11], (const float*)d_in[15]};
    const int* cluster[4] = {(const int*)d_in[4], (const int*)d_in[8], (const int*)d_in[12], (const int*)d_in[16]};
    const float* Wp[8], *Rp[8], *Bp[8];
    for (int l = 0; l < 8; ++l) {
        Wp[l] = (const float*)d_in[17 + 3 * l];
        Rp[l] = (const float*)d_in[18 + 3 * l];
        Bp[l] = (const float*)d_in[19 + 3 * l];
    }
    const float* fc1w = (const float*)d_in[41];
    const float* fc1b = (const float*)d_in[42];
    const float* fc2w = (const float*)d_in[43];
    const float* fc2b = (const float*)d_in[44];
    float* outp = (float*)d_out;

    const int NS[5] = {16384, 4096, 1024, 256, 64};
    const int ES[4] = {16384 * 8, 4096 * 8, 1024 * 8, 256 * 8};
    const int MT[4] = {2048 + 64, 512 + 64, 128 + 64, 32 + 64};
    const int TB_[4] = {0, 2112, 2112 + 576, 2112 + 576 + 192};
    const int TOT_TILES = 2112 + 576 + 192 + 96;  // 2976
    const int DOF[4] = {0, 16384, 20480, 21504};
    const int DTOT = 21760;

    char* w = (char*)d_ws;
    auto take = [&](size_t bytes) -> char* {
        char* r = w;
        w += (bytes + 255) & ~(size_t)255;
        return r;
    };
    float* bufA = (float*)take((size_t)NS[0] * 64 * 4);
    float* bufB = (float*)take((size_t)NS[0] * 64 * 4);
    unsigned* pool = (unsigned*)take((size_t)NS[1] * 64 * 4);
    size_t fallbackNeed = (size_t)(w - (char*)d_ws) + (size_t)DTOT * 4;
    int* hist = (int*)take((size_t)4 * 64 * 4);  // hist | degAll contiguous
    float* degAll = (float*)take((size_t)DTOT * 4);
    int* gcur = (int*)take((size_t)4 * 64 * 4);
    int* tileOf = (int*)take((size_t)TOT_TILES * 4);
    int* pack = (int*)take((size_t)TOT_TILES * 64 * 4);
    size_t need = (size_t)(w - (char*)d_ws);
    bool fast = ws_size >= need;

    const int TB = 256;

    if (fast) {
        // ---------- fused pre-pass: hist+deg, layout, sort (3 launches) ----
        hipMemsetAsync(hist, 0, ((size_t)4 * 64 + DTOT) * 4 + 256, stream);
        hipMemsetAsync(tileOf, 0xFF, (size_t)TOT_TILES * 4, stream);
        hist_deg_all<<<680, 256, 0, stream>>>(pseudo[0], pseudo[1], pseudo[2], pseudo[3],
                                              dst[0], dst[1], dst[2], dst[3], hist, degAll);
        scan_pad_all<<<4, 64, 0, stream>>>(hist, gcur, tileOf, pack);
        scatter_all<<<170, 256, 0, stream>>>(pseudo[0], pseudo[1], pseudo[2], pseudo[3],
                                             gcur, pack);

        // ---------------- Level 0: conv1 (1->32), conv12 (32->32) ----------
        {
            int E = ES[0], n = NS[0];
            const float* deg = degAll + DOF[0];
            hipMemsetAsync(bufA, 0, (size_t)n * 32 * 4, stream);
            conv1_fused<<<cdiv(E, 8), TB, 0, stream>>>(x, src[0], dst[0], pseudo[0], Wp[0], bufA, E);
            finalize_k<1, 32><<<cdiv(n, 8), TB, 0, stream>>>(x, Rp[0], Bp[0], deg, bufA, n);
            hipMemsetAsync(bufB, 0, (size_t)n * 32 * 4, stream);
            gemv_cube_v<32, 32><<<MT[0] * 2, TB, 0, stream>>>(
                bufA, src[0], dst[0], pseudo[0], pack, tileOf, Wp[1], bufB, TB_[0]);
            finalize_k<32, 32><<<cdiv(n, 8), TB, 0, stream>>>(bufA, Rp[1], Bp[1], deg, bufB, n);
            hipMemsetAsync(pool, 0, (size_t)NS[1] * 32 * 4, stream);
            pool_scatter<<<cdiv(n * 32, TB), TB, 0, stream>>>(bufB, cluster[0], pool, n, 5);
            pool_decode<<<cdiv(NS[1] * 32, TB), TB, 0, stream>>>(pool, bufA, NS[1] * 32);
        }
        // ---------------- Level 1: conv2 (32->64), conv3 (64->64) ----------
        {
            int n = NS[1];
            const float* deg = degAll + DOF[1];
            hipMemsetAsync(bufB, 0, (size_t)n * 64 * 4, stream);
            gemv_cube_v<32, 64><<<MT[1] * 4, TB, 0, stream>>>(
                bufA, src[1], dst[1], pseudo[1], pack, tileOf, Wp[2], bufB, TB_[1]);
            finalize_k<32, 64><<<cdiv(n, 4), TB, 0, stream>>>(bufA, Rp[2], Bp[2], deg, bufB, n);
            hipMemsetAsync(bufA, 0, (size_t)n * 64 * 4, stream);
            gemv_cube_v<64, 64><<<MT[1] * 4, TB, 0, stream>>>(
                bufB, src[1], dst[1], pseudo[1], pack, tileOf, Wp[3], bufA, TB_[1]);
            finalize_k<64, 64><<<cdiv(n, 4), TB, 0, stream>>>(bufB, Rp[3], Bp[3], deg, bufA, n);
            hipMemsetAsync(pool, 0, (size_t)NS[2] * 64 * 4, stream);
            pool_scatter<<<cdiv(n * 64, TB), TB, 0, stream>>>(bufA, cluster[1], pool, n, 6);
            pool_decode<<<cdiv(NS[2] * 64, TB), TB, 0, stream>>>(pool, bufB, NS[2] * 64);
        }
        // ---------------- Level 2: conv4, conv5 (64->64) -------------------
        {
            int n = NS[2];
            const float* deg = degAll + DOF[2];
            hipMemsetAsync(bufA, 0, (size_t)n * 64 * 4, stream);
            gemv_cube_v<64, 64><<<MT[2] * 4, TB, 0, stream>>>(
                bufB, src[2], dst[2], pseudo[2], pack, tileOf, Wp[4], bufA, TB_[2]);
            finalize_k<64, 64><<<cdiv(n, 4), TB, 0, stream>>>(bufB, Rp[4], Bp[4], deg, bufA, n);
            hipMemsetAsync(bufB, 0, (size_t)n * 64 * 4, stream);
            gemv_cube_v<64, 64><<<MT[2] * 4, TB, 0, stream>>>(
                bufA, src[2], dst[2], pseudo[2], pack, tileOf, Wp[5], bufB, TB_[2]);
            finalize_k<64, 64><<<cdiv(n, 4), TB, 0, stream>>>(bufA, Rp[5], Bp[5], deg, bufB, n);
            hipMemsetAsync(pool, 0, (size_t)NS[3] * 64 * 4, stream);
            pool_scatter<<<cdiv(n * 64, TB), TB, 0, stream>>>(bufB, cluster[2], pool, n, 6);
            pool_decode<<<cdiv(NS[3] * 64, TB), TB, 0, stream>>>(pool, bufA, NS[3] * 64);
        }
        // ---------------- Level 3: conv6, conv7 (64->64) -------------------
        {
            int n = NS[3];
            const float* deg = degAll + DOF[3];
            hipMemsetAsync(bufB, 0, (size_t)n * 64 * 4, stream);
            gemv_cube_v<64, 64><<<MT[3] * 4, TB, 0, stream>>>(
                bufA, src[3], dst[3], pseudo[3], pack, tileOf, Wp[6], bufB, TB_[3]);
            finalize_k<64, 64><<<cdiv(n, 4), TB, 0, stream>>>(bufA, Rp[6], Bp[6], deg, bufB, n);
            hipMemsetAsync(bufA, 0, (size_t)n * 64 * 4, stream);
            gemv_cube_v<64, 64><<<MT[3] * 4, TB, 0, stream>>>(
                bufB, src[3], dst[3], pseudo[3], pack, tileOf, Wp[7], bufA, TB_[3]);
            finalize_k<64, 64><<<cdiv(n, 4), TB, 0, stream>>>(bufB, Rp[7], Bp[7], deg, bufA, n);
            hipMemsetAsync(pool, 0, (size_t)NS[4] * 64 * 4, stream);
            pool_scatter<<<cdiv(n * 64, TB), TB, 0, stream>>>(bufA, cluster[3], pool, n, 6);
            pool_decode<<<cdiv(NS[4] * 64, TB), TB, 0, stream>>>(pool, bufB, NS[4] * 64);
        }
        head_kernel<<<1, 64, 0, stream>>>(bufB, fc1w, fc1b, fc2w, fc2b, outp);
    } else if (ws_size >= fallbackNeed) {
        // ---------------- legacy edge-centric fallback ---------------------
        float* h0 = bufA;
        float* h1 = bufB;
        float* deg = (float*)hist;  // reuse region
        for (int l = 0; l < 4; ++l) {
            int E = ES[l], n = NS[l];
            hipMemsetAsync(deg, 0, n * 4, stream);
            deg_kernel<<<cdiv(E, TB), TB, 0, stream>>>(dst[l], deg, E);
            for (int cc = 0; cc < 2; ++cc) {
                int li = (l == 0) ? cc : 2 * l + cc;
                if (l == 0 && cc == 0) {
                    hipMemsetAsync(h0, 0, (size_t)n * 32 * 4, stream);
                    conv1_fused<<<cdiv(E, 8), TB, 0, stream>>>(x, src[0], dst[0], pseudo[0], Wp[0], h0, E);
                    finalize_k<1, 32><<<cdiv(n, 8), TB, 0, stream>>>(x, Rp[0], Bp[0], deg, h0, n);
                } else {
                    int ic = (l == 0) ? 32 : ((l == 1 && cc == 0) ? 32 : 64);
                    int oc = (l == 0) ? 32 : 64;
                    hipMemsetAsync(h1, 0, (size_t)n * oc * 4, stream);
                    if (ic == 32 && oc == 32) {
                        conv_edges_inline<32, 32><<<cdiv(E, 8), TB, 0, stream>>>(h0, src[l], dst[l], pseudo[l], Wp[li], h1, E);
                        finalize_k<32, 32><<<cdiv(n, 8), TB, 0, stream>>>(h0, Rp[li], Bp[li], deg, h1, n);
                    } else if (ic == 32) {
                        conv_edges_inline<32, 64><<<cdiv(E, 4), TB, 0, stream>>>(h0, src[l], dst[l], pseudo[l], Wp[li], h1, E);
                        finalize_k<32, 64><<<cdiv(n, 4), TB, 0, stream>>>(h0, Rp[li], Bp[li], deg, h1, n);
                    } else {
                        conv_edges_inline<64, 64><<<cdiv(E, 4), TB, 0, stream>>>(h0, src[l], dst[l], pseudo[l], Wp[li], h1, E);
                        finalize_k<64, 64><<<cdiv(n, 4), TB, 0, stream>>>(h0, Rp[li], Bp[li], deg, h1, n);
                    }
                    float* tmp = h0; h0 = h1; h1 = tmp;
                }
            }
            int oc = (l == 0) ? 32 : 64;
            int logC = (l == 0) ? 5 : 6;
            hipMemsetAsync(pool, 0, (size_t)NS[l + 1] * oc * 4, stream);
            pool_scatter<<<cdiv(n * oc, TB), TB, 0, stream>>>(h0, cluster[l], pool, n, logC);
            pool_decode<<<cdiv(NS[l + 1] * oc, TB), TB, 0, stream>>>(pool, h1, NS[l + 1] * oc);
            float* tmp = h0; h0 = h1; h1 = tmp;
        }
        head_kernel<<<1, 64, 0, stream>>>(h0, fc1w, fc1b, fc2w, fc2b, outp);
    }
}

// Round 8
// 783.607 us; speedup vs baseline: 2.0202x; 2.0202x over previous
//
#include <hip/hip_runtime.h>
#include <hip/hip_bf16.h>

#define KS 5
#define K3 125

__device__ inline float4 f4fma(float a, float4 b, float4 c) {
    c.x = fmaf(a, b.x, c.x); c.y = fmaf(a, b.y, c.y);
    c.z = fmaf(a, b.z, c.z); c.w = fmaf(a, b.w, c.w);
    return c;
}

// ---------------------------------------------------------------------------
// Inline basis helpers
// ---------------------------------------------------------------------------
__device__ inline void edge_basis(const float* __restrict__ pseudo, int e,
                                  float* bs, int* ks) {
    float fr[3];
    int bot[3];
#pragma unroll
    for (int d = 0; d < 3; ++d) {
        float v = pseudo[e * 3 + d] * (float)(KS - 1);
        float fl = fminf(floorf(v), (float)(KS - 2));
        fr[d] = v - fl;
        bot[d] = (int)fl;
    }
    const int strides[3] = {1, KS, KS * KS};
#pragma unroll
    for (int s = 0; s < 8; ++s) {
        float b = 1.f;
        int w = 0;
#pragma unroll
        for (int d = 0; d < 3; ++d) {
            int bit = (s >> d) & 1;
            b *= bit ? fr[d] : (1.f - fr[d]);
            w += (bot[d] + bit) * strides[d];
        }
        bs[s] = b;
        ks[s] = w;
    }
}

__device__ inline int edge_bucket(const float* __restrict__ pseudo, int e) {
    int kb = 0;
#pragma unroll
    for (int d = 0; d < 3; ++d) {
        float v = pseudo[e * 3 + d] * (float)(KS - 1);
        int fl = (int)fminf(floorf(v), (float)(KS - 2));
        kb += fl << (2 * d);
    }
    return kb;
}

// ---------------------------------------------------------------------------
// Fused pass 1 (all 4 levels): 64-bucket histogram + degree.
// ---------------------------------------------------------------------------
__global__ __launch_bounds__(256) void hist_deg_all(
    const float* __restrict__ p0, const float* __restrict__ p1,
    const float* __restrict__ p2, const float* __restrict__ p3,
    const int* __restrict__ d0, const int* __restrict__ d1,
    const int* __restrict__ d2, const int* __restrict__ d3,
    int* __restrict__ hist, float* __restrict__ degAll) {
    int b = blockIdx.x;
    int l, lb, E, dof;
    const float* ps;
    const int* ds;
    if (b < 512)      { l = 0; lb = b;       ps = p0; ds = d0; E = 131072; dof = 0; }
    else if (b < 640) { l = 1; lb = b - 512; ps = p1; ds = d1; E = 32768;  dof = 16384; }
    else if (b < 672) { l = 2; lb = b - 640; ps = p2; ds = d2; E = 8192;   dof = 20480; }
    else              { l = 3; lb = b - 672; ps = p3; ds = d3; E = 2048;   dof = 21504; }
    __shared__ int h[64];
    int t = threadIdx.x;
    if (t < 64) h[t] = 0;
    __syncthreads();
    int e = lb * 256 + t;
    if (e < E) {
        atomicAdd(&h[edge_bucket(ps, e)], 1);
        atomicAdd(&degAll[dof + ds[e]], 1.f);
    }
    __syncthreads();
    if (t < 64 && h[t]) atomicAdd(&hist[l * 64 + t], h[t]);
}

// ---------------------------------------------------------------------------
// Fused pass 2: bucket layout per level (blockIdx = level).
// ---------------------------------------------------------------------------
__global__ void scan_pad_all(const int* __restrict__ hist, int* __restrict__ gcur,
                             int* __restrict__ tileOf, int* __restrict__ pack) {
    const int TBv[4] = {0, 2112, 2112 + 576, 2112 + 576 + 192};
    int l = blockIdx.x;
    int tileBase = TBv[l];
    __shared__ int sh[64];
    int t = threadIdx.x;
    int cnt = hist[l * 64 + t];
    int tiles = (cnt + 63) >> 6;
    sh[t] = tiles;
    __syncthreads();
    for (int d = 1; d < 64; d <<= 1) {
        int v = (t >= d) ? sh[t - d] : 0;
        __syncthreads();
        sh[t] += v;
        __syncthreads();
    }
    int tb = tileBase + sh[t] - tiles;
    int eb = tb * 64;
    gcur[l * 64 + t] = eb;
    for (int q = 0; q < tiles; ++q) tileOf[tb + q] = t;
    for (int idx = eb + cnt; idx < eb + tiles * 64; ++idx) pack[idx] = -1;
}

// ---------------------------------------------------------------------------
// Fused pass 3: block-local counting sort of edges (1024 edges/block).
// ---------------------------------------------------------------------------
__global__ __launch_bounds__(256) void scatter_all(
    const float* __restrict__ p0, const float* __restrict__ p1,
    const float* __restrict__ p2, const float* __restrict__ p3,
    int* __restrict__ gcur, int* __restrict__ pack) {
    int b = blockIdx.x;
    int l, lb, E;
    const float* ps;
    if (b < 128)      { l = 0; lb = b;       ps = p0; E = 131072; }
    else if (b < 160) { l = 1; lb = b - 128; ps = p1; E = 32768; }
    else if (b < 168) { l = 2; lb = b - 160; ps = p2; E = 8192; }
    else              { l = 3; lb = b - 168; ps = p3; E = 2048; }
    int* gc = gcur + l * 64;
    __shared__ int h[64], lbk[64], gb[64], sh[64];
    __shared__ int sp[1024];
    __shared__ unsigned char skk[1024];
    int t = threadIdx.x;
    int ebase = lb * 1024;
    int kbv[4];
    if (t < 64) h[t] = 0;
    __syncthreads();
#pragma unroll
    for (int j = 0; j < 4; ++j) {
        int e = ebase + j * 256 + t;
        if (e < E) {
            kbv[j] = edge_bucket(ps, e);
            atomicAdd(&h[kbv[j]], 1);
        } else
            kbv[j] = -1;
    }
    __syncthreads();
    if (t < 64) sh[t] = h[t];
    __syncthreads();
    for (int d = 1; d < 64; d <<= 1) {
        int v = (t < 64 && t >= d) ? sh[t - d] : 0;
        __syncthreads();
        if (t < 64) sh[t] += v;
        __syncthreads();
    }
    if (t < 64) {
        int c = h[t];
        lbk[t] = sh[t] - c;
        gb[t] = c ? atomicAdd(&gc[t], c) : 0;
        h[t] = 0;
    }
    __syncthreads();
#pragma unroll
    for (int j = 0; j < 4; ++j) {
        int e = ebase + j * 256 + t;
        if (kbv[j] >= 0) {
            int pos = lbk[kbv[j]] + atomicAdd(&h[kbv[j]], 1);
            sp[pos] = e;
            skk[pos] = (unsigned char)kbv[j];
        }
    }
    __syncthreads();
    int Pb = E - ebase;
    if (Pb > 1024) Pb = 1024;
    for (int j = t; j < Pb; j += 256) {
        int k = skk[j];
        pack[gb[k] + (j - lbk[k])] = sp[j];
    }
}

// ---------------------------------------------------------------------------
// Fused conv1 (in_c = 1)
// ---------------------------------------------------------------------------
__global__ __launch_bounds__(256) void conv1_fused(const float* __restrict__ x,
                                                   const int* __restrict__ src,
                                                   const int* __restrict__ dst,
                                                   const float* __restrict__ pseudo,
                                                   const float* __restrict__ W,
                                                   float* __restrict__ out, int E) {
    const int lane = threadIdx.x & 63;
    const int wid = threadIdx.x >> 6;
    const int sub = lane >> 5;
    const int o = lane & 31;
    int e = (blockIdx.x * 4 + wid) * 2 + sub;
    if (e >= E) return;
    float bs[8];
    int ks[8];
    edge_basis(pseudo, e, bs, ks);
    float acc = 0.f;
#pragma unroll
    for (int s = 0; s < 8; ++s) acc = fmaf(bs[s], W[ks[s] * 32 + o], acc);
    atomicAdd(&out[(size_t)dst[e] * 32 + o], acc * x[src[e]]);
}

// ---------------------------------------------------------------------------
// Cube GEMV v2 — register-bounded pipeline.
// Sub-group of G=OUT_C/4 lanes per edge; lane holds one float4 accumulator.
// x-row staged per-edge in LDS (wave-synchronous, padded stride 16B-aligned).
// Inner loop: i rolled (#pragma unroll 1), s(8) unrolled -> exactly 8 float4
// W loads in flight. W bases are wave-uniform (sorted cube) -> SGPR base +
// vector offset; loads pipeline via vmcnt. One atomic flush per edge.
// ---------------------------------------------------------------------------
template <int IN_C, int OUT_C>
__global__ __launch_bounds__(256) void gemv_cube_v2(
    const float* __restrict__ x, const int* __restrict__ src,
    const int* __restrict__ dst, const float* __restrict__ pseudo,
    const int* __restrict__ pack, const int* __restrict__ tileOf,
    const float* __restrict__ W, float* __restrict__ out, int tileBase) {
    constexpr int G = OUT_C / 4;   // lanes per edge
    constexpr int EPW = 64 / G;    // edges per wave
    constexpr int EPB = EPW * 4;   // edges per block (4 waves)
    constexpr int BPT = 64 / EPB;  // blocks per tile
    constexpr int XSTR = IN_C + 4; // padded x stride (16B aligned, bank-spread)
    __shared__ float xs[EPB * XSTR];
    const int tid = threadIdx.x;
    const int wv = tid >> 6, lane = tid & 63;
    const int sub = lane / G, og = lane % G;
    int t = tileBase + blockIdx.x / BPT;
    int kb = tileOf[t];
    if (kb < 0) return;  // pad tile (uniform exit)
    kb = __builtin_amdgcn_readfirstlane(kb);
    const int kbase = (kb & 3) + 5 * ((kb >> 2) & 3) + 25 * ((kb >> 4) & 3);
    const int eLoc = wv * EPW + sub;
    int e = pack[t * 64 + (blockIdx.x % BPT) * EPB + eLoc];
    float bs[8];
    float4 xq = make_float4(0.f, 0.f, 0.f, 0.f);
    int dn = -1;
    if (e >= 0) {
        float fr[3];
#pragma unroll
        for (int d = 0; d < 3; ++d) {
            float v = pseudo[e * 3 + d] * (float)(KS - 1);
            float fl = fminf(floorf(v), (float)(KS - 2));
            fr[d] = v - fl;
        }
#pragma unroll
        for (int s = 0; s < 8; ++s) {
            float b = 1.f;
#pragma unroll
            for (int d = 0; d < 3; ++d) b *= ((s >> d) & 1) ? fr[d] : (1.f - fr[d]);
            bs[s] = b;
        }
        int sn = src[e];
        dn = dst[e];
        if (og * 4 < IN_C) xq = *(const float4*)(x + (size_t)sn * IN_C + og * 4);
    } else {
#pragma unroll
        for (int s = 0; s < 8; ++s) bs[s] = 0.f;
    }
    // stage x row (wave-synchronous: writer wave == reader wave)
    if (og * 4 < IN_C) *(float4*)&xs[eLoc * XSTR + og * 4] = xq;
    constexpr int CUBE = IN_C * OUT_C;
    const float* __restrict__ Wb = W + (size_t)kbase * CUBE;
    const float* __restrict__ xr = &xs[eLoc * XSTR];
    float4 acc = make_float4(0.f, 0.f, 0.f, 0.f);
#pragma unroll 1
    for (int i = 0; i < IN_C; ++i) {
        float xi = xr[i];
#pragma unroll
        for (int s = 0; s < 8; ++s) {
            constexpr int d0 = 1, d1 = 5, d2 = 25;
            const int soff = ((s & 1) * d0 + ((s >> 1) & 1) * d1 + ((s >> 2) & 1) * d2) * CUBE;
            const float4* __restrict__ Wc = (const float4*)(Wb + soff + i * OUT_C) + og;
            acc = f4fma(bs[s] * xi, *Wc, acc);
        }
    }
    if (dn >= 0) {
        float* o = out + (size_t)dn * OUT_C + og * 4;
        atomicAdd(o + 0, acc.x);
        atomicAdd(o + 1, acc.y);
        atomicAdd(o + 2, acc.z);
        atomicAdd(o + 3, acc.w);
    }
}

// ---------------------------------------------------------------------------
// Edge-centric conv with inline basis (fallback path only)
// ---------------------------------------------------------------------------
template <int IN_C, int OUT_C>
__global__ __launch_bounds__(256) void conv_edges_inline(
    const float* __restrict__ x, const int* __restrict__ src,
    const int* __restrict__ dst, const float* __restrict__ pseudo,
    const float* __restrict__ W, float* __restrict__ out, int E) {
    const int lane = threadIdx.x & 63;
    const int wid = threadIdx.x >> 6;
    constexpr int EPW = 64 / OUT_C;
    const int sub = (EPW == 2) ? (lane >> 5) : 0;
    const int o = lane & (OUT_C - 1);
    long e = (long)(blockIdx.x * (blockDim.x >> 6) + wid) * EPW + sub;
    if (e >= E) return;
    float bs[8];
    int ks[8];
    edge_basis(pseudo, e, bs, ks);
    const int s_ = src[e];
    const int d_ = dst[e];
    float xv = (o < IN_C) ? x[s_ * IN_C + o] : 0.f;
    float acc = 0.f;
#pragma unroll
    for (int s = 0; s < 8; ++s) {
        const float b = bs[s];
        const float* Wk = W + (long)ks[s] * IN_C * OUT_C;
#pragma unroll 4
        for (int i = 0; i < IN_C; ++i) {
            float xi = __shfl(xv, i, OUT_C);
            acc = fmaf(b * xi, Wk[i * OUT_C + o], acc);
        }
    }
    atomicAdd(&out[(long)d_ * OUT_C + o], acc);
}

__global__ void deg_kernel(const int* __restrict__ dst, float* __restrict__ deg, int E) {
    int e = blockIdx.x * blockDim.x + threadIdx.x;
    if (e >= E) return;
    atomicAdd(&deg[dst[e]], 1.0f);
}

// ---------------------------------------------------------------------------
// Finalize: out = scatter/max(deg,1) + x@R + B, then ELU. In-place.
// ---------------------------------------------------------------------------
template <int IN_C, int OUT_C>
__global__ __launch_bounds__(256) void finalize_k(
    const float* __restrict__ xin, const float* __restrict__ R,
    const float* __restrict__ B, const float* __restrict__ deg,
    float* __restrict__ out, int n) {
    const int lane = threadIdx.x & 63;
    const int wid = threadIdx.x >> 6;
    constexpr int EPW = 64 / OUT_C;
    const int sub = (EPW == 2) ? (lane >> 5) : 0;
    const int o = lane & (OUT_C - 1);
    int j = (blockIdx.x * (blockDim.x >> 6) + wid) * EPW + sub;
    if (j >= n) return;
    float xv = (o < IN_C) ? xin[j * IN_C + o] : 0.f;
    float acc = B[o];
#pragma unroll 4
    for (int i = 0; i < IN_C; ++i) {
        float xi = __shfl(xv, i, OUT_C);
        acc = fmaf(xi, R[i * OUT_C + o], acc);
    }
    float d = fmaxf(deg[j], 1.f);
    float v = out[j * OUT_C + o] / d + acc;
    out[j * OUT_C + o] = (v > 0.f) ? v : expm1f(v);
}

// ---------------------------------------------------------------------------
// Segment max pooling (monotone uint atomicMax; every slot provably written)
// ---------------------------------------------------------------------------
__global__ void pool_scatter(const float* __restrict__ h, const int* __restrict__ cluster,
                             unsigned* __restrict__ pool, int n, int logC) {
    int idx = blockIdx.x * blockDim.x + threadIdx.x;
    if (idx >= (n << logC)) return;
    int j = idx >> logC;
    int c = idx & ((1 << logC) - 1);
    float f = h[idx];
    int b = __float_as_int(f);
    unsigned enc = (b >= 0) ? ((unsigned)b | 0x80000000u) : ~((unsigned)b);
    atomicMax(&pool[(cluster[j] << logC) + c], enc);
}

__global__ void pool_decode(const unsigned* __restrict__ pool, float* __restrict__ out, int total) {
    int idx = blockIdx.x * blockDim.x + threadIdx.x;
    if (idx >= total) return;
    unsigned u = pool[idx];
    int b = (u & 0x80000000u) ? (int)(u & 0x7FFFFFFFu) : (int)(~u);
    out[idx] = __int_as_float(b);
}

// ---------------------------------------------------------------------------
// Head: mean(64x64) -> fc1 -> fc2 -> log_softmax
// ---------------------------------------------------------------------------
__global__ void head_kernel(const float* __restrict__ h, const float* __restrict__ fc1w,
                            const float* __restrict__ fc1b, const float* __restrict__ fc2w,
                            const float* __restrict__ fc2b, float* __restrict__ out) {
    __shared__ float m[64], t[64], u[10];
    int lane = threadIdx.x;
    float s = 0.f;
    for (int j = 0; j < 64; ++j) s += h[j * 64 + lane];
    m[lane] = s * (1.f / 64.f);
    __syncthreads();
    float a = fc1b[lane];
    for (int i = 0; i < 64; ++i) a = fmaf(m[i], fc1w[i * 64 + lane], a);
    t[lane] = a;
    __syncthreads();
    if (lane < 10) {
        float b = fc2b[lane];
        for (int i = 0; i < 64; ++i) b = fmaf(t[i], fc2w[i * 10 + lane], b);
        u[lane] = b;
    }
    __syncthreads();
    if (lane < 10) {
        float mx = u[0];
        for (int i = 1; i < 10; ++i) mx = fmaxf(mx, u[i]);
        float se = 0.f;
        for (int i = 0; i < 10; ++i) se += expf(u[i] - mx);
        out[lane] = u[lane] - mx - logf(se);
    }
}

// ---------------------------------------------------------------------------
// Host side
// ---------------------------------------------------------------------------
static inline int cdiv(int a, int b) { return (a + b - 1) / b; }

extern "C" void kernel_launch(void* const* d_in, const int* in_sizes, int n_in,
                              void* d_out, int out_size, void* d_ws, size_t ws_size,
                              hipStream_t stream) {
    const float* x = (const float*)d_in[0];
    const int* src[4] = {(const int*)d_in[1], (const int*)d_in[5], (const int*)d_in[9], (const int*)d_in[13]};
    const int* dst[4] = {(const int*)d_in[2], (const int*)d_in[6], (const int*)d_in[10], (const int*)d_in[14]};
    const float* pseudo[4] = {(const float*)d_in[3], (const float*)d_in[7], (const float*)d_in[11], (const float*)d_in[15]};
    const int* cluster[4] = {(const int*)d_in[4], (const int*)d_in[8], (const int*)d_in[12], (const int*)d_in[16]};
    const float* Wp[8], *Rp[8], *Bp[8];
    for (int l = 0; l < 8; ++l) {
        Wp[l] = (const float*)d_in[17 + 3 * l];
        Rp[l] = (const float*)d_in[18 + 3 * l];
        Bp[l] = (const float*)d_in[19 + 3 * l];
    }
    const float* fc1w = (const float*)d_in[41];
    const float* fc1b = (const float*)d_in[42];
    const float* fc2w = (const float*)d_in[43];
    const float* fc2b = (const float*)d_in[44];
    float* outp = (float*)d_out;

    const int NS[5] = {16384, 4096, 1024, 256, 64};
    const int ES[4] = {16384 * 8, 4096 * 8, 1024 * 8, 256 * 8};
    const int MT[4] = {2048 + 64, 512 + 64, 128 + 64, 32 + 64};
    const int TB_[4] = {0, 2112, 2112 + 576, 2112 + 576 + 192};
    const int TOT_TILES = 2112 + 576 + 192 + 96;  // 2976
    const int DOF[4] = {0, 16384, 20480, 21504};
    const int DTOT = 21760;

    char* w = (char*)d_ws;
    auto take = [&](size_t bytes) -> char* {
        char* r = w;
        w += (bytes + 255) & ~(size_t)255;
        return r;
    };
    float* bufA = (float*)take((size_t)NS[0] * 64 * 4);
    float* bufB = (float*)take((size_t)NS[0] * 64 * 4);
    unsigned* pool = (unsigned*)take((size_t)NS[1] * 64 * 4);
    size_t fallbackNeed = (size_t)(w - (char*)d_ws) + (size_t)DTOT * 4;
    int* hist = (int*)take((size_t)4 * 64 * 4);  // hist | degAll contiguous
    float* degAll = (float*)take((size_t)DTOT * 4);
    int* gcur = (int*)take((size_t)4 * 64 * 4);
    int* tileOf = (int*)take((size_t)TOT_TILES * 4);
    int* pack = (int*)take((size_t)TOT_TILES * 64 * 4);
    size_t need = (size_t)(w - (char*)d_ws);
    bool fast = ws_size >= need;

    const int TB = 256;

    if (fast) {
        // ---------- fused pre-pass: hist+deg, layout, sort (3 launches) ----
        hipMemsetAsync(hist, 0, ((size_t)4 * 64 + DTOT) * 4 + 256, stream);
        hipMemsetAsync(tileOf, 0xFF, (size_t)TOT_TILES * 4, stream);
        hist_deg_all<<<680, 256, 0, stream>>>(pseudo[0], pseudo[1], pseudo[2], pseudo[3],
                                              dst[0], dst[1], dst[2], dst[3], hist, degAll);
        scan_pad_all<<<4, 64, 0, stream>>>(hist, gcur, tileOf, pack);
        scatter_all<<<170, 256, 0, stream>>>(pseudo[0], pseudo[1], pseudo[2], pseudo[3],
                                             gcur, pack);

        // ---------------- Level 0: conv1 (1->32), conv12 (32->32) ----------
        {
            int E = ES[0], n = NS[0];
            const float* deg = degAll + DOF[0];
            hipMemsetAsync(bufA, 0, (size_t)n * 32 * 4, stream);
            conv1_fused<<<cdiv(E, 8), TB, 0, stream>>>(x, src[0], dst[0], pseudo[0], Wp[0], bufA, E);
            finalize_k<1, 32><<<cdiv(n, 8), TB, 0, stream>>>(x, Rp[0], Bp[0], deg, bufA, n);
            hipMemsetAsync(bufB, 0, (size_t)n * 32 * 4, stream);
            gemv_cube_v2<32, 32><<<MT[0] * 2, TB, 0, stream>>>(
                bufA, src[0], dst[0], pseudo[0], pack, tileOf, Wp[1], bufB, TB_[0]);
            finalize_k<32, 32><<<cdiv(n, 8), TB, 0, stream>>>(bufA, Rp[1], Bp[1], deg, bufB, n);
            hipMemsetAsync(pool, 0, (size_t)NS[1] * 32 * 4, stream);
            pool_scatter<<<cdiv(n * 32, TB), TB, 0, stream>>>(bufB, cluster[0], pool, n, 5);
            pool_decode<<<cdiv(NS[1] * 32, TB), TB, 0, stream>>>(pool, bufA, NS[1] * 32);
        }
        // ---------------- Level 1: conv2 (32->64), conv3 (64->64) ----------
        {
            int n = NS[1];
            const float* deg = degAll + DOF[1];
            hipMemsetAsync(bufB, 0, (size_t)n * 64 * 4, stream);
            gemv_cube_v2<32, 64><<<MT[1] * 4, TB, 0, stream>>>(
                bufA, src[1], dst[1], pseudo[1], pack, tileOf, Wp[2], bufB, TB_[1]);
            finalize_k<32, 64><<<cdiv(n, 4), TB, 0, stream>>>(bufA, Rp[2], Bp[2], deg, bufB, n);
            hipMemsetAsync(bufA, 0, (size_t)n * 64 * 4, stream);
            gemv_cube_v2<64, 64><<<MT[1] * 4, TB, 0, stream>>>(
                bufB, src[1], dst[1], pseudo[1], pack, tileOf, Wp[3], bufA, TB_[1]);
            finalize_k<64, 64><<<cdiv(n, 4), TB, 0, stream>>>(bufB, Rp[3], Bp[3], deg, bufA, n);
            hipMemsetAsync(pool, 0, (size_t)NS[2] * 64 * 4, stream);
            pool_scatter<<<cdiv(n * 64, TB), TB, 0, stream>>>(bufA, cluster[1], pool, n, 6);
            pool_decode<<<cdiv(NS[2] * 64, TB), TB, 0, stream>>>(pool, bufB, NS[2] * 64);
        }
        // ---------------- Level 2: conv4, conv5 (64->64) -------------------
        {
            int n = NS[2];
            const float* deg = degAll + DOF[2];
            hipMemsetAsync(bufA, 0, (size_t)n * 64 * 4, stream);
            gemv_cube_v2<64, 64><<<MT[2] * 4, TB, 0, stream>>>(
                bufB, src[2], dst[2], pseudo[2], pack, tileOf, Wp[4], bufA, TB_[2]);
            finalize_k<64, 64><<<cdiv(n, 4), TB, 0, stream>>>(bufB, Rp[4], Bp[4], deg, bufA, n);
            hipMemsetAsync(bufB, 0, (size_t)n * 64 * 4, stream);
            gemv_cube_v2<64, 64><<<MT[2] * 4, TB, 0, stream>>>(
                bufA, src[2], dst[2], pseudo[2], pack, tileOf, Wp[5], bufB, TB_[2]);
            finalize_k<64, 64><<<cdiv(n, 4), TB, 0, stream>>>(bufA, Rp[5], Bp[5], deg, bufB, n);
            hipMemsetAsync(pool, 0, (size_t)NS[3] * 64 * 4, stream);
            pool_scatter<<<cdiv(n * 64, TB), TB, 0, stream>>>(bufB, cluster[2], pool, n, 6);
            pool_decode<<<cdiv(NS[3] * 64, TB), TB, 0, stream>>>(pool, bufA, NS[3] * 64);
        }
        // ---------------- Level 3: conv6, conv7 (64->64) -------------------
        {
            int n = NS[3];
            const float* deg = degAll + DOF[3];
            hipMemsetAsync(bufB, 0, (size_t)n * 64 * 4, stream);
            gemv_cube_v2<64, 64><<<MT[3] * 4, TB, 0, stream>>>(
                bufA, src[3], dst[3], pseudo[3], pack, tileOf, Wp[6], bufB, TB_[3]);
            finalize_k<64, 64><<<cdiv(n, 4), TB, 0, stream>>>(bufA, Rp[6], Bp[6], deg, bufB, n);
            hipMemsetAsync(bufA, 0, (size_t)n * 64 * 4, stream);
            gemv_cube_v2<64, 64><<<MT[3] * 4, TB, 0, stream>>>(
                bufB, src[3], dst[3], pseudo[3], pack, tileOf, Wp[7], bufA, TB_[3]);
            finalize_k<64, 64><<<cdiv(n, 4), TB, 0, stream>>>(bufB, Rp[7], Bp[7], deg, bufA, n);
            hipMemsetAsync(pool, 0, (size_t)NS[4] * 64 * 4, stream);
            pool_scatter<<<cdiv(n * 64, TB), TB, 0, stream>>>(bufA, cluster[3], pool, n, 6);
            pool_decode<<<cdiv(NS[4] * 64, TB), TB, 0, stream>>>(pool, bufB, NS[4] * 64);
        }
        head_kernel<<<1, 64, 0, stream>>>(bufB, fc1w, fc1b, fc2w, fc2b, outp);
    } else if (ws_size >= fallbackNeed) {
        // ---------------- legacy edge-centric fallback ---------------------
        float* h0 = bufA;
        float* h1 = bufB;
        float* deg = (float*)hist;  // reuse region
        for (int l = 0; l < 4; ++l) {
            int E = ES[l], n = NS[l];
            hipMemsetAsync(deg, 0, n * 4, stream);
            deg_kernel<<<cdiv(E, TB), TB, 0, stream>>>(dst[l], deg, E);
            for (int cc = 0; cc < 2; ++cc) {
                int li = (l == 0) ? cc : 2 * l + cc;
                if (l == 0 && cc == 0) {
                    hipMemsetAsync(h0, 0, (size_t)n * 32 * 4, stream);
                    conv1_fused<<<cdiv(E, 8), TB, 0, stream>>>(x, src[0], dst[0], pseudo[0], Wp[0], h0, E);
                    finalize_k<1, 32><<<cdiv(n, 8), TB, 0, stream>>>(x, Rp[0], Bp[0], deg, h0, n);
                } else {
                    int ic = (l == 0) ? 32 : ((l == 1 && cc == 0) ? 32 : 64);
                    int oc = (l == 0) ? 32 : 64;
                    hipMemsetAsync(h1, 0, (size_t)n * oc * 4, stream);
                    if (ic == 32 && oc == 32) {
                        conv_edges_inline<32, 32><<<cdiv(E, 8), TB, 0, stream>>>(h0, src[l], dst[l], pseudo[l], Wp[li], h1, E);
                        finalize_k<32, 32><<<cdiv(n, 8), TB, 0, stream>>>(h0, Rp[li], Bp[li], deg, h1, n);
                    } else if (ic == 32) {
                        conv_edges_inline<32, 64><<<cdiv(E, 4), TB, 0, stream>>>(h0, src[l], dst[l], pseudo[l], Wp[li], h1, E);
                        finalize_k<32, 64><<<cdiv(n, 4), TB, 0, stream>>>(h0, Rp[li], Bp[li], deg, h1, n);
                    } else {
                        conv_edges_inline<64, 64><<<cdiv(E, 4), TB, 0, stream>>>(h0, src[l], dst[l], pseudo[l], Wp[li], h1, E);
                        finalize_k<64, 64><<<cdiv(n, 4), TB, 0, stream>>>(h0, Rp[li], Bp[li], deg, h1, n);
                    }
                    float* tmp = h0; h0 = h1; h1 = tmp;
                }
            }
            int oc = (l == 0) ? 32 : 64;
            int logC = (l == 0) ? 5 : 6;
            hipMemsetAsync(pool, 0, (size_t)NS[l + 1] * oc * 4, stream);
            pool_scatter<<<cdiv(n * oc, TB), TB, 0, stream>>>(h0, cluster[l], pool, n, logC);
            pool_decode<<<cdiv(NS[l + 1] * oc, TB), TB, 0, stream>>>(pool, h1, NS[l + 1] * oc);
            float* tmp = h0; h0 = h1; h1 = tmp;
        }
        head_kernel<<<1, 64, 0, stream>>>(h0, fc1w, fc1b, fc2w, fc2b, outp);
    }
}

// Round 9
// 758.760 us; speedup vs baseline: 2.0863x; 1.0327x over previous
//
#include <hip/hip_runtime.h>
#include <hip/hip_bf16.h>

#define KS 5
#define K3 125

__device__ inline float4 f4fma(float a, float4 b, float4 c) {
    c.x = fmaf(a, b.x, c.x); c.y = fmaf(a, b.y, c.y);
    c.z = fmaf(a, b.z, c.z); c.w = fmaf(a, b.w, c.w);
    return c;
}

__device__ inline unsigned enc_f(float f) {
    int b = __float_as_int(f);
    return (b >= 0) ? ((unsigned)b | 0x80000000u) : ~((unsigned)b);
}

// ---------------------------------------------------------------------------
// Inline basis helpers
// ---------------------------------------------------------------------------
__device__ inline void edge_basis(const float* __restrict__ pseudo, int e,
                                  float* bs, int* ks) {
    float fr[3];
    int bot[3];
#pragma unroll
    for (int d = 0; d < 3; ++d) {
        float v = pseudo[e * 3 + d] * (float)(KS - 1);
        float fl = fminf(floorf(v), (float)(KS - 2));
        fr[d] = v - fl;
        bot[d] = (int)fl;
    }
    const int strides[3] = {1, KS, KS * KS};
#pragma unroll
    for (int s = 0; s < 8; ++s) {
        float b = 1.f;
        int w = 0;
#pragma unroll
        for (int d = 0; d < 3; ++d) {
            int bit = (s >> d) & 1;
            b *= bit ? fr[d] : (1.f - fr[d]);
            w += (bot[d] + bit) * strides[d];
        }
        bs[s] = b;
        ks[s] = w;
    }
}

__device__ inline int edge_bucket(const float* __restrict__ pseudo, int e) {
    int kb = 0;
#pragma unroll
    for (int d = 0; d < 3; ++d) {
        float v = pseudo[e * 3 + d] * (float)(KS - 1);
        int fl = (int)fminf(floorf(v), (float)(KS - 2));
        kb += fl << (2 * d);
    }
    return kb;
}

// ---------------------------------------------------------------------------
// Fused pass 1 (all 4 levels): 64-bucket histogram + degree.
// ---------------------------------------------------------------------------
__global__ __launch_bounds__(256) void hist_deg_all(
    const float* __restrict__ p0, const float* __restrict__ p1,
    const float* __restrict__ p2, const float* __restrict__ p3,
    const int* __restrict__ d0, const int* __restrict__ d1,
    const int* __restrict__ d2, const int* __restrict__ d3,
    int* __restrict__ hist, float* __restrict__ degAll) {
    int b = blockIdx.x;
    int l, lb, E, dof;
    const float* ps;
    const int* ds;
    if (b < 512)      { l = 0; lb = b;       ps = p0; ds = d0; E = 131072; dof = 0; }
    else if (b < 640) { l = 1; lb = b - 512; ps = p1; ds = d1; E = 32768;  dof = 16384; }
    else if (b < 672) { l = 2; lb = b - 640; ps = p2; ds = d2; E = 8192;   dof = 20480; }
    else              { l = 3; lb = b - 672; ps = p3; ds = d3; E = 2048;   dof = 21504; }
    __shared__ int h[64];
    int t = threadIdx.x;
    if (t < 64) h[t] = 0;
    __syncthreads();
    int e = lb * 256 + t;
    if (e < E) {
        atomicAdd(&h[edge_bucket(ps, e)], 1);
        atomicAdd(&degAll[dof + ds[e]], 1.f);
    }
    __syncthreads();
    if (t < 64 && h[t]) atomicAdd(&hist[l * 64 + t], h[t]);
}

// ---------------------------------------------------------------------------
// Fused pass 2: bucket layout per level (blockIdx = level).
// ---------------------------------------------------------------------------
__global__ void scan_pad_all(const int* __restrict__ hist, int* __restrict__ gcur,
                             int* __restrict__ tileOf, int* __restrict__ pack) {
    const int TBv[4] = {0, 2112, 2112 + 576, 2112 + 576 + 192};
    int l = blockIdx.x;
    int tileBase = TBv[l];
    __shared__ int sh[64];
    int t = threadIdx.x;
    int cnt = hist[l * 64 + t];
    int tiles = (cnt + 63) >> 6;
    sh[t] = tiles;
    __syncthreads();
    for (int d = 1; d < 64; d <<= 1) {
        int v = (t >= d) ? sh[t - d] : 0;
        __syncthreads();
        sh[t] += v;
        __syncthreads();
    }
    int tb = tileBase + sh[t] - tiles;
    int eb = tb * 64;
    gcur[l * 64 + t] = eb;
    for (int q = 0; q < tiles; ++q) tileOf[tb + q] = t;
    for (int idx = eb + cnt; idx < eb + tiles * 64; ++idx) pack[idx] = -1;
}

// ---------------------------------------------------------------------------
// Fused pass 3: block-local counting sort of edges (1024 edges/block).
// ---------------------------------------------------------------------------
__global__ __launch_bounds__(256) void scatter_all(
    const float* __restrict__ p0, const float* __restrict__ p1,
    const float* __restrict__ p2, const float* __restrict__ p3,
    int* __restrict__ gcur, int* __restrict__ pack) {
    int b = blockIdx.x;
    int l, lb, E;
    const float* ps;
    if (b < 128)      { l = 0; lb = b;       ps = p0; E = 131072; }
    else if (b < 160) { l = 1; lb = b - 128; ps = p1; E = 32768; }
    else if (b < 168) { l = 2; lb = b - 160; ps = p2; E = 8192; }
    else              { l = 3; lb = b - 168; ps = p3; E = 2048; }
    int* gc = gcur + l * 64;
    __shared__ int h[64], lbk[64], gb[64], sh[64];
    __shared__ int sp[1024];
    __shared__ unsigned char skk[1024];
    int t = threadIdx.x;
    int ebase = lb * 1024;
    int kbv[4];
    if (t < 64) h[t] = 0;
    __syncthreads();
#pragma unroll
    for (int j = 0; j < 4; ++j) {
        int e = ebase + j * 256 + t;
        if (e < E) {
            kbv[j] = edge_bucket(ps, e);
            atomicAdd(&h[kbv[j]], 1);
        } else
            kbv[j] = -1;
    }
    __syncthreads();
    if (t < 64) sh[t] = h[t];
    __syncthreads();
    for (int d = 1; d < 64; d <<= 1) {
        int v = (t < 64 && t >= d) ? sh[t - d] : 0;
        __syncthreads();
        if (t < 64) sh[t] += v;
        __syncthreads();
    }
    if (t < 64) {
        int c = h[t];
        lbk[t] = sh[t] - c;
        gb[t] = c ? atomicAdd(&gc[t], c) : 0;
        h[t] = 0;
    }
    __syncthreads();
#pragma unroll
    for (int j = 0; j < 4; ++j) {
        int e = ebase + j * 256 + t;
        if (kbv[j] >= 0) {
            int pos = lbk[kbv[j]] + atomicAdd(&h[kbv[j]], 1);
            sp[pos] = e;
            skk[pos] = (unsigned char)kbv[j];
        }
    }
    __syncthreads();
    int Pb = E - ebase;
    if (Pb > 1024) Pb = 1024;
    for (int j = t; j < Pb; j += 256) {
        int k = skk[j];
        pack[gb[k] + (j - lbk[k])] = sp[j];
    }
}

// ---------------------------------------------------------------------------
// Fused conv1 (in_c = 1)
// ---------------------------------------------------------------------------
__global__ __launch_bounds__(256) void conv1_fused(const float* __restrict__ x,
                                                   const int* __restrict__ src,
                                                   const int* __restrict__ dst,
                                                   const float* __restrict__ pseudo,
                                                   const float* __restrict__ W,
                                                   float* __restrict__ out, int E) {
    const int lane = threadIdx.x & 63;
    const int wid = threadIdx.x >> 6;
    const int sub = lane >> 5;
    const int o = lane & 31;
    int e = (blockIdx.x * 4 + wid) * 2 + sub;
    if (e >= E) return;
    float bs[8];
    int ks[8];
    edge_basis(pseudo, e, bs, ks);
    float acc = 0.f;
#pragma unroll
    for (int s = 0; s < 8; ++s) acc = fmaf(bs[s], W[ks[s] * 32 + o], acc);
    atomicAdd(&out[(size_t)dst[e] * 32 + o], acc * x[src[e]]);
}

// ---------------------------------------------------------------------------
// Cube GEMV v3 — i-loop unrolled x2 for ILP (16 float4 W loads in flight,
// ~110 VGPR, still 4 waves/SIMD). Sub-group of G=OUT_C/4 lanes per edge;
// lane holds one float4 accumulator. x-row staged per-edge in LDS
// (wave-synchronous). One coalesced atomic flush per edge.
// ---------------------------------------------------------------------------
template <int IN_C, int OUT_C>
__global__ __launch_bounds__(256) void gemv_cube_v3(
    const float* __restrict__ x, const int* __restrict__ src,
    const int* __restrict__ dst, const float* __restrict__ pseudo,
    const int* __restrict__ pack, const int* __restrict__ tileOf,
    const float* __restrict__ W, float* __restrict__ out, int tileBase) {
    constexpr int G = OUT_C / 4;   // lanes per edge
    constexpr int EPW = 64 / G;    // edges per wave
    constexpr int EPB = EPW * 4;   // edges per block (4 waves)
    constexpr int BPT = 64 / EPB;  // blocks per tile
    constexpr int XSTR = IN_C + 4; // padded x stride (16B aligned)
    __shared__ float xs[EPB * XSTR];
    const int tid = threadIdx.x;
    const int wv = tid >> 6, lane = tid & 63;
    const int sub = lane / G, og = lane % G;
    int t = tileBase + blockIdx.x / BPT;
    int kb = tileOf[t];
    if (kb < 0) return;  // pad tile (uniform exit)
    kb = __builtin_amdgcn_readfirstlane(kb);
    const int kbase = (kb & 3) + 5 * ((kb >> 2) & 3) + 25 * ((kb >> 4) & 3);
    const int eLoc = wv * EPW + sub;
    int e = pack[t * 64 + (blockIdx.x % BPT) * EPB + eLoc];
    float bs[8];
    float4 xq = make_float4(0.f, 0.f, 0.f, 0.f);
    int dn = -1;
    if (e >= 0) {
        float fr[3];
#pragma unroll
        for (int d = 0; d < 3; ++d) {
            float v = pseudo[e * 3 + d] * (float)(KS - 1);
            float fl = fminf(floorf(v), (float)(KS - 2));
            fr[d] = v - fl;
        }
#pragma unroll
        for (int s = 0; s < 8; ++s) {
            float b = 1.f;
#pragma unroll
            for (int d = 0; d < 3; ++d) b *= ((s >> d) & 1) ? fr[d] : (1.f - fr[d]);
            bs[s] = b;
        }
        int sn = src[e];
        dn = dst[e];
        if (og * 4 < IN_C) xq = *(const float4*)(x + (size_t)sn * IN_C + og * 4);
    } else {
#pragma unroll
        for (int s = 0; s < 8; ++s) bs[s] = 0.f;
    }
    // stage x row (wave-synchronous: writer wave == reader wave)
    if (og * 4 < IN_C) *(float4*)&xs[eLoc * XSTR + og * 4] = xq;
    constexpr int CUBE = IN_C * OUT_C;
    const float* __restrict__ Wb = W + (size_t)kbase * CUBE;
    const float* __restrict__ xr = &xs[eLoc * XSTR];
    float4 acc = make_float4(0.f, 0.f, 0.f, 0.f);
#pragma unroll 1
    for (int i = 0; i < IN_C; i += 2) {
        float2 xi2 = *(const float2*)&xr[i];
#pragma unroll
        for (int s = 0; s < 8; ++s) {
            const int soff = ((s & 1) + 5 * ((s >> 1) & 1) + 25 * ((s >> 2) & 1)) * CUBE;
            const float4* __restrict__ Wc = (const float4*)(Wb + soff + i * OUT_C) + og;
            acc = f4fma(bs[s] * xi2.x, Wc[0], acc);
            acc = f4fma(bs[s] * xi2.y, Wc[G], acc);
        }
    }
    if (dn >= 0) {
        float* o = out + (size_t)dn * OUT_C + og * 4;
        atomicAdd(o + 0, acc.x);
        atomicAdd(o + 1, acc.y);
        atomicAdd(o + 2, acc.z);
        atomicAdd(o + 3, acc.w);
    }
}

// ---------------------------------------------------------------------------
// Edge-centric conv with inline basis (fallback path only)
// ---------------------------------------------------------------------------
template <int IN_C, int OUT_C>
__global__ __launch_bounds__(256) void conv_edges_inline(
    const float* __restrict__ x, const int* __restrict__ src,
    const int* __restrict__ dst, const float* __restrict__ pseudo,
    const float* __restrict__ W, float* __restrict__ out, int E) {
    const int lane = threadIdx.x & 63;
    const int wid = threadIdx.x >> 6;
    constexpr int EPW = 64 / OUT_C;
    const int sub = (EPW == 2) ? (lane >> 5) : 0;
    const int o = lane & (OUT_C - 1);
    long e = (long)(blockIdx.x * (blockDim.x >> 6) + wid) * EPW + sub;
    if (e >= E) return;
    float bs[8];
    int ks[8];
    edge_basis(pseudo, e, bs, ks);
    const int s_ = src[e];
    const int d_ = dst[e];
    float xv = (o < IN_C) ? x[s_ * IN_C + o] : 0.f;
    float acc = 0.f;
#pragma unroll
    for (int s = 0; s < 8; ++s) {
        const float b = bs[s];
        const float* Wk = W + (long)ks[s] * IN_C * OUT_C;
#pragma unroll 4
        for (int i = 0; i < IN_C; ++i) {
            float xi = __shfl(xv, i, OUT_C);
            acc = fmaf(b * xi, Wk[i * OUT_C + o], acc);
        }
    }
    atomicAdd(&out[(long)d_ * OUT_C + o], acc);
}

__global__ void deg_kernel(const int* __restrict__ dst, float* __restrict__ deg, int E) {
    int e = blockIdx.x * blockDim.x + threadIdx.x;
    if (e >= E) return;
    atomicAdd(&deg[dst[e]], 1.0f);
}

// ---------------------------------------------------------------------------
// Finalize: out = scatter/max(deg,1) + x@R + B, then ELU. In-place.
// ---------------------------------------------------------------------------
template <int IN_C, int OUT_C>
__global__ __launch_bounds__(256) void finalize_k(
    const float* __restrict__ xin, const float* __restrict__ R,
    const float* __restrict__ B, const float* __restrict__ deg,
    float* __restrict__ out, int n) {
    const int lane = threadIdx.x & 63;
    const int wid = threadIdx.x >> 6;
    constexpr int EPW = 64 / OUT_C;
    const int sub = (EPW == 2) ? (lane >> 5) : 0;
    const int o = lane & (OUT_C - 1);
    int j = (blockIdx.x * (blockDim.x >> 6) + wid) * EPW + sub;
    if (j >= n) return;
    float xv = (o < IN_C) ? xin[j * IN_C + o] : 0.f;
    float acc = B[o];
#pragma unroll 4
    for (int i = 0; i < IN_C; ++i) {
        float xi = __shfl(xv, i, OUT_C);
        acc = fmaf(xi, R[i * OUT_C + o], acc);
    }
    float d = fmaxf(deg[j], 1.f);
    float v = out[j * OUT_C + o] / d + acc;
    out[j * OUT_C + o] = (v > 0.f) ? v : expm1f(v);
}

// ---------------------------------------------------------------------------
// Finalize + fused max-pool scatter (level-ending conv): computes the ELU'd
// value, writes it, and atomicMax-es its encoding into the pool buffer.
// ---------------------------------------------------------------------------
template <int IN_C, int OUT_C>
__global__ __launch_bounds__(256) void finalize_pool_k(
    const float* __restrict__ xin, const float* __restrict__ R,
    const float* __restrict__ B, const float* __restrict__ deg,
    const int* __restrict__ cluster, unsigned* __restrict__ pool,
    float* __restrict__ out, int n) {
    constexpr int LOGC = (OUT_C == 32) ? 5 : 6;
    const int lane = threadIdx.x & 63;
    const int wid = threadIdx.x >> 6;
    constexpr int EPW = 64 / OUT_C;
    const int sub = (EPW == 2) ? (lane >> 5) : 0;
    const int o = lane & (OUT_C - 1);
    int j = (blockIdx.x * (blockDim.x >> 6) + wid) * EPW + sub;
    if (j >= n) return;
    float xv = (o < IN_C) ? xin[j * IN_C + o] : 0.f;
    float acc = B[o];
#pragma unroll 4
    for (int i = 0; i < IN_C; ++i) {
        float xi = __shfl(xv, i, OUT_C);
        acc = fmaf(xi, R[i * OUT_C + o], acc);
    }
    float d = fmaxf(deg[j], 1.f);
    float v = out[j * OUT_C + o] / d + acc;
    v = (v > 0.f) ? v : expm1f(v);
    out[j * OUT_C + o] = v;
    atomicMax(&pool[(cluster[j] << LOGC) + o], enc_f(v));
}

// ---------------------------------------------------------------------------
// Segment max pooling (fallback path) + decode
// ---------------------------------------------------------------------------
__global__ void pool_scatter(const float* __restrict__ h, const int* __restrict__ cluster,
                             unsigned* __restrict__ pool, int n, int logC) {
    int idx = blockIdx.x * blockDim.x + threadIdx.x;
    if (idx >= (n << logC)) return;
    int j = idx >> logC;
    int c = idx & ((1 << logC) - 1);
    atomicMax(&pool[(cluster[j] << logC) + c], enc_f(h[idx]));
}

__global__ void pool_decode(const unsigned* __restrict__ pool, float* __restrict__ out, int total) {
    int idx = blockIdx.x * blockDim.x + threadIdx.x;
    if (idx >= total) return;
    unsigned u = pool[idx];
    int b = (u & 0x80000000u) ? (int)(u & 0x7FFFFFFFu) : (int)(~u);
    out[idx] = __int_as_float(b);
}

// ---------------------------------------------------------------------------
// Head: mean(64x64) -> fc1 -> fc2 -> log_softmax
// ---------------------------------------------------------------------------
__global__ void head_kernel(const float* __restrict__ h, const float* __restrict__ fc1w,
                            const float* __restrict__ fc1b, const float* __restrict__ fc2w,
                            const float* __restrict__ fc2b, float* __restrict__ out) {
    __shared__ float m[64], t[64], u[10];
    int lane = threadIdx.x;
    float s = 0.f;
    for (int j = 0; j < 64; ++j) s += h[j * 64 + lane];
    m[lane] = s * (1.f / 64.f);
    __syncthreads();
    float a = fc1b[lane];
    for (int i = 0; i < 64; ++i) a = fmaf(m[i], fc1w[i * 64 + lane], a);
    t[lane] = a;
    __syncthreads();
    if (lane < 10) {
        float b = fc2b[lane];
        for (int i = 0; i < 64; ++i) b = fmaf(t[i], fc2w[i * 10 + lane], b);
        u[lane] = b;
    }
    __syncthreads();
    if (lane < 10) {
        float mx = u[0];
        for (int i = 1; i < 10; ++i) mx = fmaxf(mx, u[i]);
        float se = 0.f;
        for (int i = 0; i < 10; ++i) se += expf(u[i] - mx);
        out[lane] = u[lane] - mx - logf(se);
    }
}

// ---------------------------------------------------------------------------
// Host side
// ---------------------------------------------------------------------------
static inline int cdiv(int a, int b) { return (a + b - 1) / b; }

extern "C" void kernel_launch(void* const* d_in, const int* in_sizes, int n_in,
                              void* d_out, int out_size, void* d_ws, size_t ws_size,
                              hipStream_t stream) {
    const float* x = (const float*)d_in[0];
    const int* src[4] = {(const int*)d_in[1], (const int*)d_in[5], (const int*)d_in[9], (const int*)d_in[13]};
    const int* dst[4] = {(const int*)d_in[2], (const int*)d_in[6], (const int*)d_in[10], (const int*)d_in[14]};
    const float* pseudo[4] = {(const float*)d_in[3], (const float*)d_in[7], (const float*)d_in[11], (const float*)d_in[15]};
    const int* cluster[4] = {(const int*)d_in[4], (const int*)d_in[8], (const int*)d_in[12], (const int*)d_in[16]};
    const float* Wp[8], *Rp[8], *Bp[8];
    for (int l = 0; l < 8; ++l) {
        Wp[l] = (const float*)d_in[17 + 3 * l];
        Rp[l] = (const float*)d_in[18 + 3 * l];
        Bp[l] = (const float*)d_in[19 + 3 * l];
    }
    const float* fc1w = (const float*)d_in[41];
    const float* fc1b = (const float*)d_in[42];
    const float* fc2w = (const float*)d_in[43];
    const float* fc2b = (const float*)d_in[44];
    float* outp = (float*)d_out;

    const int NS[5] = {16384, 4096, 1024, 256, 64};
    const int ES[4] = {16384 * 8, 4096 * 8, 1024 * 8, 256 * 8};
    const int MT[4] = {2048 + 64, 512 + 64, 128 + 64, 32 + 64};
    const int TB_[4] = {0, 2112, 2112 + 576, 2112 + 576 + 192};
    const int TOT_TILES = 2112 + 576 + 192 + 96;  // 2976
    const int DOF[4] = {0, 16384, 20480, 21504};
    const int DTOT = 21760;

    char* w = (char*)d_ws;
    auto take = [&](size_t bytes) -> char* {
        char* r = w;
        w += (bytes + 255) & ~(size_t)255;
        return r;
    };
    float* bufA = (float*)take((size_t)NS[0] * 64 * 4);
    float* bufB = (float*)take((size_t)NS[0] * 64 * 4);
    unsigned* pool = (unsigned*)take((size_t)NS[1] * 64 * 4);
    size_t fallbackNeed = (size_t)(w - (char*)d_ws) + (size_t)DTOT * 4;
    int* hist = (int*)take((size_t)4 * 64 * 4);  // hist | degAll contiguous
    float* degAll = (float*)take((size_t)DTOT * 4);
    int* gcur = (int*)take((size_t)4 * 64 * 4);
    int* tileOf = (int*)take((size_t)TOT_TILES * 4);
    int* pack = (int*)take((size_t)TOT_TILES * 64 * 4);
    size_t need = (size_t)(w - (char*)d_ws);
    bool fast = ws_size >= need;

    const int TB = 256;

    if (fast) {
        // ---------- fused pre-pass: hist+deg, layout, sort (3 launches) ----
        hipMemsetAsync(hist, 0, ((size_t)4 * 64 + DTOT) * 4 + 256, stream);
        hipMemsetAsync(tileOf, 0xFF, (size_t)TOT_TILES * 4, stream);
        hist_deg_all<<<680, 256, 0, stream>>>(pseudo[0], pseudo[1], pseudo[2], pseudo[3],
                                              dst[0], dst[1], dst[2], dst[3], hist, degAll);
        scan_pad_all<<<4, 64, 0, stream>>>(hist, gcur, tileOf, pack);
        scatter_all<<<170, 256, 0, stream>>>(pseudo[0], pseudo[1], pseudo[2], pseudo[3],
                                             gcur, pack);

        // ---------------- Level 0: conv1 (1->32), conv12 (32->32) ----------
        {
            int E = ES[0], n = NS[0];
            const float* deg = degAll + DOF[0];
            hipMemsetAsync(bufA, 0, (size_t)n * 32 * 4, stream);
            conv1_fused<<<cdiv(E, 8), TB, 0, stream>>>(x, src[0], dst[0], pseudo[0], Wp[0], bufA, E);
            finalize_k<1, 32><<<cdiv(n, 8), TB, 0, stream>>>(x, Rp[0], Bp[0], deg, bufA, n);
            hipMemsetAsync(bufB, 0, (size_t)n * 32 * 4, stream);
            hipMemsetAsync(pool, 0, (size_t)NS[1] * 32 * 4, stream);
            gemv_cube_v3<32, 32><<<MT[0] * 2, TB, 0, stream>>>(
                bufA, src[0], dst[0], pseudo[0], pack, tileOf, Wp[1], bufB, TB_[0]);
            finalize_pool_k<32, 32><<<cdiv(n, 8), TB, 0, stream>>>(
                bufA, Rp[1], Bp[1], deg, cluster[0], pool, bufB, n);
            pool_decode<<<cdiv(NS[1] * 32, TB), TB, 0, stream>>>(pool, bufA, NS[1] * 32);
        }
        // ---------------- Level 1: conv2 (32->64), conv3 (64->64) ----------
        {
            int n = NS[1];
            const float* deg = degAll + DOF[1];
            hipMemsetAsync(bufB, 0, (size_t)n * 64 * 4, stream);
            gemv_cube_v3<32, 64><<<MT[1] * 4, TB, 0, stream>>>(
                bufA, src[1], dst[1], pseudo[1], pack, tileOf, Wp[2], bufB, TB_[1]);
            finalize_k<32, 64><<<cdiv(n, 4), TB, 0, stream>>>(bufA, Rp[2], Bp[2], deg, bufB, n);
            hipMemsetAsync(bufA, 0, (size_t)n * 64 * 4, stream);
            hipMemsetAsync(pool, 0, (size_t)NS[2] * 64 * 4, stream);
            gemv_cube_v3<64, 64><<<MT[1] * 4, TB, 0, stream>>>(
                bufB, src[1], dst[1], pseudo[1], pack, tileOf, Wp[3], bufA, TB_[1]);
            finalize_pool_k<64, 64><<<cdiv(n, 4), TB, 0, stream>>>(
                bufB, Rp[3], Bp[3], deg, cluster[1], pool, bufA, n);
            pool_decode<<<cdiv(NS[2] * 64, TB), TB, 0, stream>>>(pool, bufB, NS[2] * 64);
        }
        // ---------------- Level 2: conv4, conv5 (64->64) -------------------
        {
            int n = NS[2];
            const float* deg = degAll + DOF[2];
            hipMemsetAsync(bufA, 0, (size_t)n * 64 * 4, stream);
            gemv_cube_v3<64, 64><<<MT[2] * 4, TB, 0, stream>>>(
                bufB, src[2], dst[2], pseudo[2], pack, tileOf, Wp[4], bufA, TB_[2]);
            finalize_k<64, 64><<<cdiv(n, 4), TB, 0, stream>>>(bufB, Rp[4], Bp[4], deg, bufA, n);
            hipMemsetAsync(bufB, 0, (size_t)n * 64 * 4, stream);
            hipMemsetAsync(pool, 0, (size_t)NS[3] * 64 * 4, stream);
            gemv_cube_v3<64, 64><<<MT[2] * 4, TB, 0, stream>>>(
                bufA, src[2], dst[2], pseudo[2], pack, tileOf, Wp[5], bufB, TB_[2]);
            finalize_pool_k<64, 64><<<cdiv(n, 4), TB, 0, stream>>>(
                bufA, Rp[5], Bp[5], deg, cluster[2], pool, bufB, n);
            pool_decode<<<cdiv(NS[3] * 64, TB), TB, 0, stream>>>(pool, bufA, NS[3] * 64);
        }
        // ---------------- Level 3: conv6, conv7 (64->64) -------------------
        {
            int n = NS[3];
            const float* deg = degAll + DOF[3];
            hipMemsetAsync(bufB, 0, (size_t)n * 64 * 4, stream);
            gemv_cube_v3<64, 64><<<MT[3] * 4, TB, 0, stream>>>(
                bufA, src[3], dst[3], pseudo[3], pack, tileOf, Wp[6], bufB, TB_[3]);
            finalize_k<64, 64><<<cdiv(n, 4), TB, 0, stream>>>(bufA, Rp[6], Bp[6], deg, bufB, n);
            hipMemsetAsync(bufA, 0, (size_t)n * 64 * 4, stream);
            hipMemsetAsync(pool, 0, (size_t)NS[4] * 64 * 4, stream);
            gemv_cube_v3<64, 64><<<MT[3] * 4, TB, 0, stream>>>(
                bufB, src[3], dst[3], pseudo[3], pack, tileOf, Wp[7], bufA, TB_[3]);
            finalize_pool_k<64, 64><<<cdiv(n, 4), TB, 0, stream>>>(
                bufB, Rp[7], Bp[7], deg, cluster[3], pool, bufA, n);
            pool_decode<<<cdiv(NS[4] * 64, TB), TB, 0, stream>>>(pool, bufB, NS[4] * 64);
        }
        head_kernel<<<1, 64, 0, stream>>>(bufB, fc1w, fc1b, fc2w, fc2b, outp);
    } else if (ws_size >= fallbackNeed) {
        // ---------------- legacy edge-centric fallback ---------------------
        float* h0 = bufA;
        float* h1 = bufB;
        float* deg = (float*)hist;  // reuse region
        for (int l = 0; l < 4; ++l) {
            int E = ES[l], n = NS[l];
            hipMemsetAsync(deg, 0, n * 4, stream);
            deg_kernel<<<cdiv(E, TB), TB, 0, stream>>>(dst[l], deg, E);
            for (int cc = 0; cc < 2; ++cc) {
                int li = (l == 0) ? cc : 2 * l + cc;
                if (l == 0 && cc == 0) {
                    hipMemsetAsync(h0, 0, (size_t)n * 32 * 4, stream);
                    conv1_fused<<<cdiv(E, 8), TB, 0, stream>>>(x, src[0], dst[0], pseudo[0], Wp[0], h0, E);
                    finalize_k<1, 32><<<cdiv(n, 8), TB, 0, stream>>>(x, Rp[0], Bp[0], deg, h0, n);
                } else {
                    int ic = (l == 0) ? 32 : ((l == 1 && cc == 0) ? 32 : 64);
                    int oc = (l == 0) ? 32 : 64;
                    hipMemsetAsync(h1, 0, (size_t)n * oc * 4, stream);
                    if (ic == 32 && oc == 32) {
                        conv_edges_inline<32, 32><<<cdiv(E, 8), TB, 0, stream>>>(h0, src[l], dst[l], pseudo[l], Wp[li], h1, E);
                        finalize_k<32, 32><<<cdiv(n, 8), TB, 0, stream>>>(h0, Rp[li], Bp[li], deg, h1, n);
                    } else if (ic == 32) {
                        conv_edges_inline<32, 64><<<cdiv(E, 4), TB, 0, stream>>>(h0, src[l], dst[l], pseudo[l], Wp[li], h1, E);
                        finalize_k<32, 64><<<cdiv(n, 4), TB, 0, stream>>>(h0, Rp[li], Bp[li], deg, h1, n);
                    } else {
                        conv_edges_inline<64, 64><<<cdiv(E, 4), TB, 0, stream>>>(h0, src[l], dst[l], pseudo[l], Wp[li], h1, E);
                        finalize_k<64, 64><<<cdiv(n, 4), TB, 0, stream>>>(h0, Rp[li], Bp[li], deg, h1, n);
                    }
                    float* tmp = h0; h0 = h1; h1 = tmp;
                }
            }
            int oc = (l == 0) ? 32 : 64;
            int logC = (l == 0) ? 5 : 6;
            hipMemsetAsync(pool, 0, (size_t)NS[l + 1] * oc * 4, stream);
            pool_scatter<<<cdiv(n * oc, TB), TB, 0, stream>>>(h0, cluster[l], pool, n, logC);
            pool_decode<<<cdiv(NS[l + 1] * oc, TB), TB, 0, stream>>>(pool, h1, NS[l + 1] * oc);
            float* tmp = h0; h0 = h1; h1 = tmp;
        }
        head_kernel<<<1, 64, 0, stream>>>(h0, fc1w, fc1b, fc2w, fc2b, outp);
    }
}

// Round 10
// 617.911 us; speedup vs baseline: 2.5619x; 1.2279x over previous
//
#include <hip/hip_runtime.h>
#include <hip/hip_bf16.h>

#define KS 5
#define K3 125

__device__ inline float4 f4fma(float a, float4 b, float4 c) {
    c.x = fmaf(a, b.x, c.x); c.y = fmaf(a, b.y, c.y);
    c.z = fmaf(a, b.z, c.z); c.w = fmaf(a, b.w, c.w);
    return c;
}

__device__ inline unsigned enc_f(float f) {
    int b = __float_as_int(f);
    return (b >= 0) ? ((unsigned)b | 0x80000000u) : ~((unsigned)b);
}

// ---------------------------------------------------------------------------
// Inline basis helpers
// ---------------------------------------------------------------------------
__device__ inline void edge_basis(const float* __restrict__ pseudo, int e,
                                  float* bs, int* ks) {
    float fr[3];
    int bot[3];
#pragma unroll
    for (int d = 0; d < 3; ++d) {
        float v = pseudo[e * 3 + d] * (float)(KS - 1);
        float fl = fminf(floorf(v), (float)(KS - 2));
        fr[d] = v - fl;
        bot[d] = (int)fl;
    }
    const int strides[3] = {1, KS, KS * KS};
#pragma unroll
    for (int s = 0; s < 8; ++s) {
        float b = 1.f;
        int w = 0;
#pragma unroll
        for (int d = 0; d < 3; ++d) {
            int bit = (s >> d) & 1;
            b *= bit ? fr[d] : (1.f - fr[d]);
            w += (bot[d] + bit) * strides[d];
        }
        bs[s] = b;
        ks[s] = w;
    }
}

__device__ inline void edge_fracs(const float* __restrict__ pseudo, int e, float* bs) {
    float fr[3];
#pragma unroll
    for (int d = 0; d < 3; ++d) {
        float v = pseudo[e * 3 + d] * (float)(KS - 1);
        float fl = fminf(floorf(v), (float)(KS - 2));
        fr[d] = v - fl;
    }
#pragma unroll
    for (int s = 0; s < 8; ++s) {
        float b = 1.f;
#pragma unroll
        for (int d = 0; d < 3; ++d) b *= ((s >> d) & 1) ? fr[d] : (1.f - fr[d]);
        bs[s] = b;
    }
}

__device__ inline int edge_bucket(const float* __restrict__ pseudo, int e) {
    int kb = 0;
#pragma unroll
    for (int d = 0; d < 3; ++d) {
        float v = pseudo[e * 3 + d] * (float)(KS - 1);
        int fl = (int)fminf(floorf(v), (float)(KS - 2));
        kb += fl << (2 * d);
    }
    return kb;
}

// ---------------------------------------------------------------------------
// Fused pass 1 (all 4 levels): 64-bucket histogram + degree.
// ---------------------------------------------------------------------------
__global__ __launch_bounds__(256) void hist_deg_all(
    const float* __restrict__ p0, const float* __restrict__ p1,
    const float* __restrict__ p2, const float* __restrict__ p3,
    const int* __restrict__ d0, const int* __restrict__ d1,
    const int* __restrict__ d2, const int* __restrict__ d3,
    int* __restrict__ hist, float* __restrict__ degAll) {
    int b = blockIdx.x;
    int l, lb, E, dof;
    const float* ps;
    const int* ds;
    if (b < 512)      { l = 0; lb = b;       ps = p0; ds = d0; E = 131072; dof = 0; }
    else if (b < 640) { l = 1; lb = b - 512; ps = p1; ds = d1; E = 32768;  dof = 16384; }
    else if (b < 672) { l = 2; lb = b - 640; ps = p2; ds = d2; E = 8192;   dof = 20480; }
    else              { l = 3; lb = b - 672; ps = p3; ds = d3; E = 2048;   dof = 21504; }
    __shared__ int h[64];
    int t = threadIdx.x;
    if (t < 64) h[t] = 0;
    __syncthreads();
    int e = lb * 256 + t;
    if (e < E) {
        atomicAdd(&h[edge_bucket(ps, e)], 1);
        atomicAdd(&degAll[dof + ds[e]], 1.f);
    }
    __syncthreads();
    if (t < 64 && h[t]) atomicAdd(&hist[l * 64 + t], h[t]);
}

// ---------------------------------------------------------------------------
// Fused pass 2: bucket layout per level (blockIdx = level).
// ---------------------------------------------------------------------------
__global__ void scan_pad_all(const int* __restrict__ hist, int* __restrict__ gcur,
                             int* __restrict__ tileOf, int* __restrict__ pack) {
    const int TBv[4] = {0, 2112, 2112 + 576, 2112 + 576 + 192};
    int l = blockIdx.x;
    int tileBase = TBv[l];
    __shared__ int sh[64];
    int t = threadIdx.x;
    int cnt = hist[l * 64 + t];
    int tiles = (cnt + 63) >> 6;
    sh[t] = tiles;
    __syncthreads();
    for (int d = 1; d < 64; d <<= 1) {
        int v = (t >= d) ? sh[t - d] : 0;
        __syncthreads();
        sh[t] += v;
        __syncthreads();
    }
    int tb = tileBase + sh[t] - tiles;
    int eb = tb * 64;
    gcur[l * 64 + t] = eb;
    for (int q = 0; q < tiles; ++q) tileOf[tb + q] = t;
    for (int idx = eb + cnt; idx < eb + tiles * 64; ++idx) pack[idx] = -1;
}

// ---------------------------------------------------------------------------
// Fused pass 3: block-local counting sort of edges (1024 edges/block).
// ---------------------------------------------------------------------------
__global__ __launch_bounds__(256) void scatter_all(
    const float* __restrict__ p0, const float* __restrict__ p1,
    const float* __restrict__ p2, const float* __restrict__ p3,
    int* __restrict__ gcur, int* __restrict__ pack) {
    int b = blockIdx.x;
    int l, lb, E;
    const float* ps;
    if (b < 128)      { l = 0; lb = b;       ps = p0; E = 131072; }
    else if (b < 160) { l = 1; lb = b - 128; ps = p1; E = 32768; }
    else if (b < 168) { l = 2; lb = b - 160; ps = p2; E = 8192; }
    else              { l = 3; lb = b - 168; ps = p3; E = 2048; }
    int* gc = gcur + l * 64;
    __shared__ int h[64], lbk[64], gb[64], sh[64];
    __shared__ int sp[1024];
    __shared__ unsigned char skk[1024];
    int t = threadIdx.x;
    int ebase = lb * 1024;
    int kbv[4];
    if (t < 64) h[t] = 0;
    __syncthreads();
#pragma unroll
    for (int j = 0; j < 4; ++j) {
        int e = ebase + j * 256 + t;
        if (e < E) {
            kbv[j] = edge_bucket(ps, e);
            atomicAdd(&h[kbv[j]], 1);
        } else
            kbv[j] = -1;
    }
    __syncthreads();
    if (t < 64) sh[t] = h[t];
    __syncthreads();
    for (int d = 1; d < 64; d <<= 1) {
        int v = (t < 64 && t >= d) ? sh[t - d] : 0;
        __syncthreads();
        if (t < 64) sh[t] += v;
        __syncthreads();
    }
    if (t < 64) {
        int c = h[t];
        lbk[t] = sh[t] - c;
        gb[t] = c ? atomicAdd(&gc[t], c) : 0;
        h[t] = 0;
    }
    __syncthreads();
#pragma unroll
    for (int j = 0; j < 4; ++j) {
        int e = ebase + j * 256 + t;
        if (kbv[j] >= 0) {
            int pos = lbk[kbv[j]] + atomicAdd(&h[kbv[j]], 1);
            sp[pos] = e;
            skk[pos] = (unsigned char)kbv[j];
        }
    }
    __syncthreads();
    int Pb = E - ebase;
    if (Pb > 1024) Pb = 1024;
    for (int j = t; j < Pb; j += 256) {
        int k = skk[j];
        pack[gb[k] + (j - lbk[k])] = sp[j];
    }
}

// ---------------------------------------------------------------------------
// Fused conv1 (in_c = 1)
// ---------------------------------------------------------------------------
__global__ __launch_bounds__(256) void conv1_fused(const float* __restrict__ x,
                                                   const int* __restrict__ src,
                                                   const int* __restrict__ dst,
                                                   const float* __restrict__ pseudo,
                                                   const float* __restrict__ W,
                                                   float* __restrict__ out, int E) {
    const int lane = threadIdx.x & 63;
    const int wid = threadIdx.x >> 6;
    const int sub = lane >> 5;
    const int o = lane & 31;
    int e = (blockIdx.x * 4 + wid) * 2 + sub;
    if (e >= E) return;
    float bs[8];
    int ks[8];
    edge_basis(pseudo, e, bs, ks);
    float acc = 0.f;
#pragma unroll
    for (int s = 0; s < 8; ++s) acc = fmaf(bs[s], W[ks[s] * 32 + o], acc);
    atomicAdd(&out[(size_t)dst[e] * 32 + o], acc * x[src[e]]);
}

// ---------------------------------------------------------------------------
// Cube GEMV v4 — 2 edges per sub-group (each W load feeds 2 accumulators,
// halving VMEM per FMA) + explicit 16-wide load batch pinned with
// sched_barrier(0) so the compiler must keep all 16 float4 in flight
// (fixes R9's VGPR=32 serialized-waitcnt stall). One atomic flush per edge.
// ---------------------------------------------------------------------------
template <int IN_C, int OUT_C>
__global__ __launch_bounds__(256) void gemv_cube_v4(
    const float* __restrict__ x, const int* __restrict__ src,
    const int* __restrict__ dst, const float* __restrict__ pseudo,
    const int* __restrict__ pack, const int* __restrict__ tileOf,
    const float* __restrict__ W, float* __restrict__ out, int tileBase) {
    constexpr int G = OUT_C / 4;    // lanes per sub-group
    constexpr int SG = 64 / G;      // sub-groups per wave
    constexpr int EPW = 2 * SG;     // edges per wave
    constexpr int EPB = 4 * EPW;    // edges per block
    constexpr int BPT = 64 / EPB;   // blocks per tile (1 or 2)
    constexpr int XSTR = IN_C + 4;  // padded x stride
    __shared__ float xs[EPB * XSTR];
    const int tid = threadIdx.x;
    const int wv = tid >> 6, lane = tid & 63;
    const int sg = lane / G, og = lane % G;
    int t = tileBase + blockIdx.x / BPT;
    int kb = tileOf[t];
    if (kb < 0) return;  // pad tile (uniform exit)
    kb = __builtin_amdgcn_readfirstlane(kb);
    const int kbase = (kb & 3) + 5 * ((kb >> 2) & 3) + 25 * ((kb >> 4) & 3);
    const int eL0 = wv * EPW + sg * 2;  // local indices of this sub-group's edges
    const int eL1 = eL0 + 1;
    const int gbase = t * 64 + (blockIdx.x % BPT) * EPB;
    int e0 = pack[gbase + eL0];
    int e1 = pack[gbase + eL1];
    float bs0[8], bs1[8];
    int dn0 = -1, dn1 = -1;
    float4 xq0 = make_float4(0.f, 0.f, 0.f, 0.f);
    float4 xq1 = make_float4(0.f, 0.f, 0.f, 0.f);
    if (e0 >= 0) {
        edge_fracs(pseudo, e0, bs0);
        dn0 = dst[e0];
        if (og * 4 < IN_C) xq0 = *(const float4*)(x + (size_t)src[e0] * IN_C + og * 4);
    } else {
#pragma unroll
        for (int s = 0; s < 8; ++s) bs0[s] = 0.f;
    }
    if (e1 >= 0) {
        edge_fracs(pseudo, e1, bs1);
        dn1 = dst[e1];
        if (og * 4 < IN_C) xq1 = *(const float4*)(x + (size_t)src[e1] * IN_C + og * 4);
    } else {
#pragma unroll
        for (int s = 0; s < 8; ++s) bs1[s] = 0.f;
    }
    // stage both x rows (wave-synchronous: same-wave LDS ops are in order)
    if (og * 4 < IN_C) {
        *(float4*)&xs[eL0 * XSTR + og * 4] = xq0;
        *(float4*)&xs[eL1 * XSTR + og * 4] = xq1;
    }
    constexpr int CUBE = IN_C * OUT_C;
    const float* __restrict__ Wb = W + (size_t)kbase * CUBE;
    const float* __restrict__ xr0 = &xs[eL0 * XSTR];
    const float* __restrict__ xr1 = &xs[eL1 * XSTR];
    float4 acc0 = make_float4(0.f, 0.f, 0.f, 0.f);
    float4 acc1 = make_float4(0.f, 0.f, 0.f, 0.f);
#pragma unroll 1
    for (int i = 0; i < IN_C; i += 2) {
        float2 xa = *(const float2*)&xr0[i];
        float2 xb = *(const float2*)&xr1[i];
        float4 wreg[16];
#pragma unroll
        for (int s = 0; s < 8; ++s) {
            const int soff = ((s & 1) + 5 * ((s >> 1) & 1) + 25 * ((s >> 2) & 1)) * CUBE;
            const float4* __restrict__ Wc = (const float4*)(Wb + soff + i * OUT_C) + og;
            wreg[2 * s] = Wc[0];
            wreg[2 * s + 1] = Wc[G];
        }
        __builtin_amdgcn_sched_barrier(0);  // pin: all 16 loads in flight before fmas
#pragma unroll
        for (int s = 0; s < 8; ++s) {
            acc0 = f4fma(bs0[s] * xa.x, wreg[2 * s], acc0);
            acc0 = f4fma(bs0[s] * xa.y, wreg[2 * s + 1], acc0);
            acc1 = f4fma(bs1[s] * xb.x, wreg[2 * s], acc1);
            acc1 = f4fma(bs1[s] * xb.y, wreg[2 * s + 1], acc1);
        }
    }
    if (dn0 >= 0) {
        float* o = out + (size_t)dn0 * OUT_C + og * 4;
        atomicAdd(o + 0, acc0.x);
        atomicAdd(o + 1, acc0.y);
        atomicAdd(o + 2, acc0.z);
        atomicAdd(o + 3, acc0.w);
    }
    if (dn1 >= 0) {
        float* o = out + (size_t)dn1 * OUT_C + og * 4;
        atomicAdd(o + 0, acc1.x);
        atomicAdd(o + 1, acc1.y);
        atomicAdd(o + 2, acc1.z);
        atomicAdd(o + 3, acc1.w);
    }
}

// ---------------------------------------------------------------------------
// Edge-centric conv with inline basis (fallback path only)
// ---------------------------------------------------------------------------
template <int IN_C, int OUT_C>
__global__ __launch_bounds__(256) void conv_edges_inline(
    const float* __restrict__ x, const int* __restrict__ src,
    const int* __restrict__ dst, const float* __restrict__ pseudo,
    const float* __restrict__ W, float* __restrict__ out, int E) {
    const int lane = threadIdx.x & 63;
    const int wid = threadIdx.x >> 6;
    constexpr int EPW = 64 / OUT_C;
    const int sub = (EPW == 2) ? (lane >> 5) : 0;
    const int o = lane & (OUT_C - 1);
    long e = (long)(blockIdx.x * (blockDim.x >> 6) + wid) * EPW + sub;
    if (e >= E) return;
    float bs[8];
    int ks[8];
    edge_basis(pseudo, e, bs, ks);
    const int s_ = src[e];
    const int d_ = dst[e];
    float xv = (o < IN_C) ? x[s_ * IN_C + o] : 0.f;
    float acc = 0.f;
#pragma unroll
    for (int s = 0; s < 8; ++s) {
        const float b = bs[s];
        const float* Wk = W + (long)ks[s] * IN_C * OUT_C;
#pragma unroll 4
        for (int i = 0; i < IN_C; ++i) {
            float xi = __shfl(xv, i, OUT_C);
            acc = fmaf(b * xi, Wk[i * OUT_C + o], acc);
        }
    }
    atomicAdd(&out[(long)d_ * OUT_C + o], acc);
}

__global__ void deg_kernel(const int* __restrict__ dst, float* __restrict__ deg, int E) {
    int e = blockIdx.x * blockDim.x + threadIdx.x;
    if (e >= E) return;
    atomicAdd(&deg[dst[e]], 1.0f);
}

// ---------------------------------------------------------------------------
// Finalize: out = scatter/max(deg,1) + x@R + B, then ELU. In-place.
// ---------------------------------------------------------------------------
template <int IN_C, int OUT_C>
__global__ __launch_bounds__(256) void finalize_k(
    const float* __restrict__ xin, const float* __restrict__ R,
    const float* __restrict__ B, const float* __restrict__ deg,
    float* __restrict__ out, int n) {
    const int lane = threadIdx.x & 63;
    const int wid = threadIdx.x >> 6;
    constexpr int EPW = 64 / OUT_C;
    const int sub = (EPW == 2) ? (lane >> 5) : 0;
    const int o = lane & (OUT_C - 1);
    int j = (blockIdx.x * (blockDim.x >> 6) + wid) * EPW + sub;
    if (j >= n) return;
    float xv = (o < IN_C) ? xin[j * IN_C + o] : 0.f;
    float acc = B[o];
#pragma unroll 4
    for (int i = 0; i < IN_C; ++i) {
        float xi = __shfl(xv, i, OUT_C);
        acc = fmaf(xi, R[i * OUT_C + o], acc);
    }
    float d = fmaxf(deg[j], 1.f);
    float v = out[j * OUT_C + o] / d + acc;
    out[j * OUT_C + o] = (v > 0.f) ? v : expm1f(v);
}

// ---------------------------------------------------------------------------
// Finalize + fused max-pool scatter (level-ending conv)
// ---------------------------------------------------------------------------
template <int IN_C, int OUT_C>
__global__ __launch_bounds__(256) void finalize_pool_k(
    const float* __restrict__ xin, const float* __restrict__ R,
    const float* __restrict__ B, const float* __restrict__ deg,
    const int* __restrict__ cluster, unsigned* __restrict__ pool,
    float* __restrict__ out, int n) {
    constexpr int LOGC = (OUT_C == 32) ? 5 : 6;
    const int lane = threadIdx.x & 63;
    const int wid = threadIdx.x >> 6;
    constexpr int EPW = 64 / OUT_C;
    const int sub = (EPW == 2) ? (lane >> 5) : 0;
    const int o = lane & (OUT_C - 1);
    int j = (blockIdx.x * (blockDim.x >> 6) + wid) * EPW + sub;
    if (j >= n) return;
    float xv = (o < IN_C) ? xin[j * IN_C + o] : 0.f;
    float acc = B[o];
#pragma unroll 4
    for (int i = 0; i < IN_C; ++i) {
        float xi = __shfl(xv, i, OUT_C);
        acc = fmaf(xi, R[i * OUT_C + o], acc);
    }
    float d = fmaxf(deg[j], 1.f);
    float v = out[j * OUT_C + o] / d + acc;
    v = (v > 0.f) ? v : expm1f(v);
    out[j * OUT_C + o] = v;
    atomicMax(&pool[(cluster[j] << LOGC) + o], enc_f(v));
}

// ---------------------------------------------------------------------------
// Segment max pooling (fallback path) + decode
// ---------------------------------------------------------------------------
__global__ void pool_scatter(const float* __restrict__ h, const int* __restrict__ cluster,
                             unsigned* __restrict__ pool, int n, int logC) {
    int idx = blockIdx.x * blockDim.x + threadIdx.x;
    if (idx >= (n << logC)) return;
    int j = idx >> logC;
    int c = idx & ((1 << logC) - 1);
    atomicMax(&pool[(cluster[j] << logC) + c], enc_f(h[idx]));
}

__global__ void pool_decode(const unsigned* __restrict__ pool, float* __restrict__ out, int total) {
    int idx = blockIdx.x * blockDim.x + threadIdx.x;
    if (idx >= total) return;
    unsigned u = pool[idx];
    int b = (u & 0x80000000u) ? (int)(u & 0x7FFFFFFFu) : (int)(~u);
    out[idx] = __int_as_float(b);
}

// ---------------------------------------------------------------------------
// Head: mean(64x64) -> fc1 -> fc2 -> log_softmax
// ---------------------------------------------------------------------------
__global__ void head_kernel(const float* __restrict__ h, const float* __restrict__ fc1w,
                            const float* __restrict__ fc1b, const float* __restrict__ fc2w,
                            const float* __restrict__ fc2b, float* __restrict__ out) {
    __shared__ float m[64], t[64], u[10];
    int lane = threadIdx.x;
    float s = 0.f;
    for (int j = 0; j < 64; ++j) s += h[j * 64 + lane];
    m[lane] = s * (1.f / 64.f);
    __syncthreads();
    float a = fc1b[lane];
    for (int i = 0; i < 64; ++i) a = fmaf(m[i], fc1w[i * 64 + lane], a);
    t[lane] = a;
    __syncthreads();
    if (lane < 10) {
        float b = fc2b[lane];
        for (int i = 0; i < 64; ++i) b = fmaf(t[i], fc2w[i * 10 + lane], b);
        u[lane] = b;
    }
    __syncthreads();
    if (lane < 10) {
        float mx = u[0];
        for (int i = 1; i < 10; ++i) mx = fmaxf(mx, u[i]);
        float se = 0.f;
        for (int i = 0; i < 10; ++i) se += expf(u[i] - mx);
        out[lane] = u[lane] - mx - logf(se);
    }
}

// ---------------------------------------------------------------------------
// Host side
// ---------------------------------------------------------------------------
static inline int cdiv(int a, int b) { return (a + b - 1) / b; }

extern "C" void kernel_launch(void* const* d_in, const int* in_sizes, int n_in,
                              void* d_out, int out_size, void* d_ws, size_t ws_size,
                              hipStream_t stream) {
    const float* x = (const float*)d_in[0];
    const int* src[4] = {(const int*)d_in[1], (const int*)d_in[5], (const int*)d_in[9], (const int*)d_in[13]};
    const int* dst[4] = {(const int*)d_in[2], (const int*)d_in[6], (const int*)d_in[10], (const int*)d_in[14]};
    const float* pseudo[4] = {(const float*)d_in[3], (const float*)d_in[7], (const float*)d_in[11], (const float*)d_in[15]};
    const int* cluster[4] = {(const int*)d_in[4], (const int*)d_in[8], (const int*)d_in[12], (const int*)d_in[16]};
    const float* Wp[8], *Rp[8], *Bp[8];
    for (int l = 0; l < 8; ++l) {
        Wp[l] = (const float*)d_in[17 + 3 * l];
        Rp[l] = (const float*)d_in[18 + 3 * l];
        Bp[l] = (const float*)d_in[19 + 3 * l];
    }
    const float* fc1w = (const float*)d_in[41];
    const float* fc1b = (const float*)d_in[42];
    const float* fc2w = (const float*)d_in[43];
    const float* fc2b = (const float*)d_in[44];
    float* outp = (float*)d_out;

    const int NS[5] = {16384, 4096, 1024, 256, 64};
    const int ES[4] = {16384 * 8, 4096 * 8, 1024 * 8, 256 * 8};
    const int MT[4] = {2048 + 64, 512 + 64, 128 + 64, 32 + 64};
    const int TB_[4] = {0, 2112, 2112 + 576, 2112 + 576 + 192};
    const int TOT_TILES = 2112 + 576 + 192 + 96;  // 2976
    const int DOF[4] = {0, 16384, 20480, 21504};
    const int DTOT = 21760;

    char* w = (char*)d_ws;
    auto take = [&](size_t bytes) -> char* {
        char* r = w;
        w += (bytes + 255) & ~(size_t)255;
        return r;
    };
    float* bufA = (float*)take((size_t)NS[0] * 64 * 4);
    float* bufB = (float*)take((size_t)NS[0] * 64 * 4);
    unsigned* pool = (unsigned*)take((size_t)NS[1] * 64 * 4);
    size_t fallbackNeed = (size_t)(w - (char*)d_ws) + (size_t)DTOT * 4;
    int* hist = (int*)take((size_t)4 * 64 * 4);  // hist | degAll contiguous
    float* degAll = (float*)take((size_t)DTOT * 4);
    int* gcur = (int*)take((size_t)4 * 64 * 4);
    int* tileOf = (int*)take((size_t)TOT_TILES * 4);
    int* pack = (int*)take((size_t)TOT_TILES * 64 * 4);
    size_t need = (size_t)(w - (char*)d_ws);
    bool fast = ws_size >= need;

    const int TB = 256;

    if (fast) {
        // ---------- fused pre-pass: hist+deg, layout, sort (3 launches) ----
        hipMemsetAsync(hist, 0, ((size_t)4 * 64 + DTOT) * 4 + 256, stream);
        hipMemsetAsync(tileOf, 0xFF, (size_t)TOT_TILES * 4, stream);
        hist_deg_all<<<680, 256, 0, stream>>>(pseudo[0], pseudo[1], pseudo[2], pseudo[3],
                                              dst[0], dst[1], dst[2], dst[3], hist, degAll);
        scan_pad_all<<<4, 64, 0, stream>>>(hist, gcur, tileOf, pack);
        scatter_all<<<170, 256, 0, stream>>>(pseudo[0], pseudo[1], pseudo[2], pseudo[3],
                                             gcur, pack);

        // ---------------- Level 0: conv1 (1->32), conv12 (32->32) ----------
        {
            int E = ES[0], n = NS[0];
            const float* deg = degAll + DOF[0];
            hipMemsetAsync(bufA, 0, (size_t)n * 32 * 4, stream);
            conv1_fused<<<cdiv(E, 8), TB, 0, stream>>>(x, src[0], dst[0], pseudo[0], Wp[0], bufA, E);
            finalize_k<1, 32><<<cdiv(n, 8), TB, 0, stream>>>(x, Rp[0], Bp[0], deg, bufA, n);
            hipMemsetAsync(bufB, 0, (size_t)n * 32 * 4, stream);
            hipMemsetAsync(pool, 0, (size_t)NS[1] * 32 * 4, stream);
            gemv_cube_v4<32, 32><<<MT[0], TB, 0, stream>>>(
                bufA, src[0], dst[0], pseudo[0], pack, tileOf, Wp[1], bufB, TB_[0]);
            finalize_pool_k<32, 32><<<cdiv(n, 8), TB, 0, stream>>>(
                bufA, Rp[1], Bp[1], deg, cluster[0], pool, bufB, n);
            pool_decode<<<cdiv(NS[1] * 32, TB), TB, 0, stream>>>(pool, bufA, NS[1] * 32);
        }
        // ---------------- Level 1: conv2 (32->64), conv3 (64->64) ----------
        {
            int n = NS[1];
            const float* deg = degAll + DOF[1];
            hipMemsetAsync(bufB, 0, (size_t)n * 64 * 4, stream);
            gemv_cube_v4<32, 64><<<MT[1] * 2, TB, 0, stream>>>(
                bufA, src[1], dst[1], pseudo[1], pack, tileOf, Wp[2], bufB, TB_[1]);
            finalize_k<32, 64><<<cdiv(n, 4), TB, 0, stream>>>(bufA, Rp[2], Bp[2], deg, bufB, n);
            hipMemsetAsync(bufA, 0, (size_t)n * 64 * 4, stream);
            hipMemsetAsync(pool, 0, (size_t)NS[2] * 64 * 4, stream);
            gemv_cube_v4<64, 64><<<MT[1] * 2, TB, 0, stream>>>(
                bufB, src[1], dst[1], pseudo[1], pack, tileOf, Wp[3], bufA, TB_[1]);
            finalize_pool_k<64, 64><<<cdiv(n, 4), TB, 0, stream>>>(
                bufB, Rp[3], Bp[3], deg, cluster[1], pool, bufA, n);
            pool_decode<<<cdiv(NS[2] * 64, TB), TB, 0, stream>>>(pool, bufB, NS[2] * 64);
        }
        // ---------------- Level 2: conv4, conv5 (64->64) -------------------
        {
            int n = NS[2];
            const float* deg = degAll + DOF[2];
            hipMemsetAsync(bufA, 0, (size_t)n * 64 * 4, stream);
            gemv_cube_v4<64, 64><<<MT[2] * 2, TB, 0, stream>>>(
                bufB, src[2], dst[2], pseudo[2], pack, tileOf, Wp[4], bufA, TB_[2]);
            finalize_k<64, 64><<<cdiv(n, 4), TB, 0, stream>>>(bufB, Rp[4], Bp[4], deg, bufA, n);
            hipMemsetAsync(bufB, 0, (size_t)n * 64 * 4, stream);
            hipMemsetAsync(pool, 0, (size_t)NS[3] * 64 * 4, stream);
            gemv_cube_v4<64, 64><<<MT[2] * 2, TB, 0, stream>>>(
                bufA, src[2], dst[2], pseudo[2], pack, tileOf, Wp[5], bufB, TB_[2]);
            finalize_pool_k<64, 64><<<cdiv(n, 4), TB, 0, stream>>>(
                bufA, Rp[5], Bp[5], deg, cluster[2], pool, bufB, n);
            pool_decode<<<cdiv(NS[3] * 64, TB), TB, 0, stream>>>(pool, bufA, NS[3] * 64);
        }
        // ---------------- Level 3: conv6, conv7 (64->64) -------------------
        {
            int n = NS[3];
            const float* deg = degAll + DOF[3];
            hipMemsetAsync(bufB, 0, (size_t)n * 64 * 4, stream);
            gemv_cube_v4<64, 64><<<MT[3] * 2, TB, 0, stream>>>(
                bufA, src[3], dst[3], pseudo[3], pack, tileOf, Wp[6], bufB, TB_[3]);
            finalize_k<64, 64><<<cdiv(n, 4), TB, 0, stream>>>(bufA, Rp[6], Bp[6], deg, bufB, n);
            hipMemsetAsync(bufA, 0, (size_t)n * 64 * 4, stream);
            hipMemsetAsync(pool, 0, (size_t)NS[4] * 64 * 4, stream);
            gemv_cube_v4<64, 64><<<MT[3] * 2, TB, 0, stream>>>(
                bufB, src[3], dst[3], pseudo[3], pack, tileOf, Wp[7], bufA, TB_[3]);
            finalize_pool_k<64, 64><<<cdiv(n, 4), TB, 0, stream>>>(
                bufB, Rp[7], Bp[7], deg, cluster[3], pool, bufA, n);
            pool_decode<<<cdiv(NS[4] * 64, TB), TB, 0, stream>>>(pool, bufB, NS[4] * 64);
        }
        head_kernel<<<1, 64, 0, stream>>>(bufB, fc1w, fc1b, fc2w, fc2b, outp);
    } else if (ws_size >= fallbackNeed) {
        // ---------------- legacy edge-centric fallback ---------------------
        float* h0 = bufA;
        float* h1 = bufB;
        float* deg = (float*)hist;  // reuse region
        for (int l = 0; l < 4; ++l) {
            int E = ES[l], n = NS[l];
            hipMemsetAsync(deg, 0, n * 4, stream);
            deg_kernel<<<cdiv(E, TB), TB, 0, stream>>>(dst[l], deg, E);
            for (int cc = 0; cc < 2; ++cc) {
                int li = (l == 0) ? cc : 2 * l + cc;
                if (l == 0 && cc == 0) {
                    hipMemsetAsync(h0, 0, (size_t)n * 32 * 4, stream);
                    conv1_fused<<<cdiv(E, 8), TB, 0, stream>>>(x, src[0], dst[0], pseudo[0], Wp[0], h0, E);
                    finalize_k<1, 32><<<cdiv(n, 8), TB, 0, stream>>>(x, Rp[0], Bp[0], deg, h0, n);
                } else {
                    int ic = (l == 0) ? 32 : ((l == 1 && cc == 0) ? 32 : 64);
                    int oc = (l == 0) ? 32 : 64;
                    hipMemsetAsync(h1, 0, (size_t)n * oc * 4, stream);
                    if (ic == 32 && oc == 32) {
                        conv_edges_inline<32, 32><<<cdiv(E, 8), TB, 0, stream>>>(h0, src[l], dst[l], pseudo[l], Wp[li], h1, E);
                        finalize_k<32, 32><<<cdiv(n, 8), TB, 0, stream>>>(h0, Rp[li], Bp[li], deg, h1, n);
                    } else if (ic == 32) {
                        conv_edges_inline<32, 64><<<cdiv(E, 4), TB, 0, stream>>>(h0, src[l], dst[l], pseudo[l], Wp[li], h1, E);
                        finalize_k<32, 64><<<cdiv(n, 4), TB, 0, stream>>>(h0, Rp[li], Bp[li], deg, h1, n);
                    } else {
                        conv_edges_inline<64, 64><<<cdiv(E, 4), TB, 0, stream>>>(h0, src[l], dst[l], pseudo[l], Wp[li], h1, E);
                        finalize_k<64, 64><<<cdiv(n, 4), TB, 0, stream>>>(h0, Rp[li], Bp[li], deg, h1, n);
                    }
                    float* tmp = h0; h0 = h1; h1 = tmp;
                }
            }
            int oc = (l == 0) ? 32 : 64;
            int logC = (l == 0) ? 5 : 6;
            hipMemsetAsync(pool, 0, (size_t)NS[l + 1] * oc * 4, stream);
            pool_scatter<<<cdiv(n * oc, TB), TB, 0, stream>>>(h0, cluster[l], pool, n, logC);
            pool_decode<<<cdiv(NS[l + 1] * oc, TB), TB, 0, stream>>>(pool, h1, NS[l + 1] * oc);
            float* tmp = h0; h0 = h1; h1 = tmp;
        }
        head_kernel<<<1, 64, 0, stream>>>(h0, fc1w, fc1b, fc2w, fc2b, outp);
    }
}